// Round 8
// baseline (748.947 us; speedup 1.0000x reference)
//
#include <hip/hip_runtime.h>
#include <math.h>

#define NN 100000
#define NE 1600000
#define DD 128
#define NL 3
#define LN_EPS 1e-5f
#define NRANGE 8
#define RSZ (NN / NRANGE)  // 12500

typedef __attribute__((ext_vector_type(8))) short bf16x8;
typedef __attribute__((ext_vector_type(4))) float f32x4;
typedef unsigned short ushort_t;

__device__ __forceinline__ short f2bf(float f) {
  unsigned u = __float_as_uint(f);
  unsigned r = (u + 0x7fffu + ((u >> 16) & 1u)) >> 16;
  return (short)r;
}
__device__ __forceinline__ float bf2f(short s) {
  return __uint_as_float(((unsigned)(unsigned short)s) << 16);
}
__device__ __forceinline__ unsigned short f2h(float f) {
  _Float16 h = (_Float16)f;
  unsigned short u;
  __builtin_memcpy(&u, &h, 2);
  return u;
}
__device__ __forceinline__ float h2f(unsigned short u) {
  _Float16 h;
  __builtin_memcpy(&h, &u, 2);
  return (float)h;
}
// gelu with fast erf (A&S 7.1.26, |err|<1.5e-7 -- far below tolerance)
__device__ __forceinline__ float gelu_fast(float x) {
  float xs = x * 0.7071067811865476f;
  float ax = fabsf(xs);
  float t = __builtin_amdgcn_rcpf(fmaf(0.3275911f, ax, 1.0f));
  float p = fmaf(t, 1.061405429f, -1.453152027f);
  p = fmaf(t, p, 1.421413741f);
  p = fmaf(t, p, -0.284496736f);
  p = fmaf(t, p, 0.254829592f);
  p = p * t;
  float e = __expf(-ax * ax);
  float er = fmaf(-p, e, 1.0f);
  er = copysignf(er, xs);
  return 0.5f * x * (1.0f + er);
}

// ---------------- CSR build (XCD-ranged scatters) ----------------
__global__ __launch_bounds__(256) void k_count(const int* __restrict__ dst,
                                               int* __restrict__ deg) {
  int range = blockIdx.x & (NRANGE - 1);
  int lo = range * RSZ;
  int hi = lo + RSZ;  // NN divisible by 8
  int nblk = gridDim.x >> 3;
  int bid = blockIdx.x >> 3;
  for (int e = bid * 256 + threadIdx.x; e < NE; e += nblk * 256) {
    int d = dst[e];
    if (d >= lo && d < hi) atomicAdd(&deg[d], 1);
  }
}

__global__ void k_block_sums(const int* __restrict__ deg, int* __restrict__ bsum) {
  __shared__ int sh[256];
  int t = threadIdx.x;
  int base = blockIdx.x * 1024;
  int s = 0;
#pragma unroll
  for (int j = 0; j < 4; j++) {
    int idx = base + t * 4 + j;
    if (idx < NN) s += deg[idx];
  }
  sh[t] = s;
  __syncthreads();
  for (int off = 128; off > 0; off >>= 1) {
    if (t < off) sh[t] += sh[t + off];
    __syncthreads();
  }
  if (t == 0) bsum[blockIdx.x] = sh[0];
}

__global__ void k_scan_sums(int* __restrict__ bsum, int nb) {
  __shared__ int sh[128];
  int t = threadIdx.x;
  int v = (t < nb) ? bsum[t] : 0;
  int acc = v;
  sh[t] = v;
  __syncthreads();
  for (int off = 1; off < 128; off <<= 1) {
    int o = (t >= off) ? sh[t - off] : 0;
    __syncthreads();
    acc += o;
    sh[t] = acc;
    __syncthreads();
  }
  if (t < nb) bsum[t] = acc - v;  // exclusive
}

__global__ void k_scan_write(const int* __restrict__ deg, const int* __restrict__ bsum,
                             int* __restrict__ rowstart) {
  __shared__ int sh[256];
  int t = threadIdx.x;
  int base = blockIdx.x * 1024;
  int idx0 = base + t * 4;
  int v[4];
  int s = 0;
#pragma unroll
  for (int j = 0; j < 4; j++) {
    int idx = idx0 + j;
    v[j] = (idx < NN) ? deg[idx] : 0;
    s += v[j];
  }
  int acc = s;
  sh[t] = s;
  __syncthreads();
  for (int off = 1; off < 256; off <<= 1) {
    int o = (t >= off) ? sh[t - off] : 0;
    __syncthreads();
    acc += o;
    sh[t] = acc;
    __syncthreads();
  }
  int excl = acc - s + bsum[blockIdx.x];
#pragma unroll
  for (int j = 0; j < 4; j++) {
    int idx = idx0 + j;
    if (idx < NN) rowstart[idx] = excl;
    excl += v[j];
  }
  if (blockIdx.x == 0 && t == 0) rowstart[NN] = NE;
}

__global__ __launch_bounds__(256) void k_fill(const int* __restrict__ src,
                                              const int* __restrict__ dst,
                                              const int* __restrict__ rowstart,
                                              int* __restrict__ cursor,
                                              int* __restrict__ csr) {
  int range = blockIdx.x & (NRANGE - 1);
  int lo = range * RSZ;
  int hi = lo + RSZ;
  int nblk = gridDim.x >> 3;
  int bid = blockIdx.x >> 3;
  for (int e = bid * 256 + threadIdx.x; e < NE; e += nblk * 256) {
    int d = dst[e];
    if (d >= lo && d < hi) {
      int p = atomicAdd(&cursor[d], 1);
      csr[rowstart[d] + p] = src[e];
    }
  }
}

// ---------------- W pre-pack into MFMA A-of-W^T fragment order (split bf16) --
// W1, pW: k = 32kk + 8q + j (natural order).
// W2:     k = 32kk + 16(j>>2) + 4q + (j&3) -- permutation that makes the
//         GEMM2 B-fragment equal the GEMM1' accumulator layout (no LDS xpose).
__global__ void k_pack(const float* __restrict__ W1, const float* __restrict__ W2,
                       const float* __restrict__ pW, short* __restrict__ hi,
                       short* __restrict__ lo) {
  int id = blockIdx.x * 256 + threadIdx.x;  // 7*16384
  int mtx = id >> 14;                       // 0..6
  int r = id & 16383;
  const float* src;
  int perm = 0;
  if (mtx == 6) {
    src = pW;  // natural pack: k_mm consumes memory-layout B-frags
  } else {
    int layer = mtx >> 1;
    if (mtx & 1) {
      src = W2 + layer * 16384;
      perm = 1;
    } else {
      src = W1 + layer * 16384;
    }
  }
  int j = r & 7;
  int l = (r >> 3) & 63;
  int kk = (r >> 9) & 3;
  int t = r >> 11;
  int qq = (l >> 4) & 3;
  int k = perm ? (kk * 32 + ((j >> 2) << 4) + (qq << 2) + (j & 3))
               : (kk * 32 + (qq << 3) + j);
  int n = t * 16 + (l & 15);
  float w = src[k * DD + n];
  short h = f2bf(w);
  hi[id] = h;
  lo[id] = f2bf(w - bf2f(h));
}

// ---------------- x -> fp16 h0 ----------------
__global__ void k_cast(const float* __restrict__ x, ushort_t* __restrict__ hb) {
  int i = blockIdx.x * 256 + threadIdx.x;  // over NN*DD/4
  if (i < NN * DD / 4) {
    float4 v = ((const float4*)x)[i];
    ushort4 o;
    o.x = f2h(v.x);
    o.y = f2h(v.y);
    o.z = f2h(v.z);
    o.w = f2h(v.w);
    ((ushort4*)hb)[i] = o;
  }
}

// ---- gather: z = (1+eps)*hb[n] + sum_{incoming} hb[src] (all fp16) -> split bf16
__global__ __launch_bounds__(256) void k_gather(const ushort_t* __restrict__ hb,
                                                const int* __restrict__ rowstart,
                                                const int* __restrict__ csr,
                                                const float* __restrict__ eps, int layer,
                                                unsigned* __restrict__ zhi,
                                                unsigned* __restrict__ zlo) {
  int n = blockIdx.x * 4 + (threadIdx.x >> 6);
  int t = threadIdx.x & 63;  // column pair 0..63
  const unsigned* hb2 = (const unsigned*)hb;
  unsigned sv = hb2[(size_t)n * 64 + t];
  float e1 = 1.0f + eps[layer];
  float a0 = e1 * h2f((ushort_t)(sv & 0xffffu));
  float a1 = e1 * h2f((ushort_t)(sv >> 16));
  float b0 = 0.f, b1 = 0.f, c0 = 0.f, c1 = 0.f, d0 = 0.f, d1 = 0.f;
  int s = rowstart[n], e = rowstart[n + 1];
  int k = s;
  for (; k + 3 < e; k += 4) {
    int n0 = csr[k], n1 = csr[k + 1], n2 = csr[k + 2], n3 = csr[k + 3];
    unsigned v0 = hb2[(size_t)n0 * 64 + t];
    unsigned v1 = hb2[(size_t)n1 * 64 + t];
    unsigned v2 = hb2[(size_t)n2 * 64 + t];
    unsigned v3 = hb2[(size_t)n3 * 64 + t];
    a0 += h2f((ushort_t)(v0 & 0xffffu));
    a1 += h2f((ushort_t)(v0 >> 16));
    b0 += h2f((ushort_t)(v1 & 0xffffu));
    b1 += h2f((ushort_t)(v1 >> 16));
    c0 += h2f((ushort_t)(v2 & 0xffffu));
    c1 += h2f((ushort_t)(v2 >> 16));
    d0 += h2f((ushort_t)(v3 & 0xffffu));
    d1 += h2f((ushort_t)(v3 >> 16));
  }
  for (; k < e; k++) {
    unsigned v = hb2[(size_t)csr[k] * 64 + t];
    a0 += h2f((ushort_t)(v & 0xffffu));
    a1 += h2f((ushort_t)(v >> 16));
  }
  a0 += (b0 + c0) + d0;
  a1 += (b1 + c1) + d1;
  short h0 = f2bf(a0), h1 = f2bf(a1);
  short l0 = f2bf(a0 - bf2f(h0)), l1 = f2bf(a1 - bf2f(h1));
  unsigned ph = (unsigned)(ushort_t)h0 | ((unsigned)(ushort_t)h1 << 16);
  unsigned pl = (unsigned)(ushort_t)l0 | ((unsigned)(ushort_t)l1 << 16);
  zhi[(size_t)n * 64 + t] = ph;
  zlo[(size_t)n * 64 + t] = pl;
}

// ------- fused MLP: swapped-operand, LDS-free, 2 node-tiles per wave ---------
// Each wave owns 32 nodes (2 x 16-node tiles). Every weight-fragment load now
// feeds 6 MFMAs (2 tiles x 3 split-bf16 products) instead of 3 -> weight
// traffic per node halves and the MFMA drain per 16-load batch (~48 MFMAs)
// covers the next batch's L2 latency. Epilogues run per-tile to cap VGPRs.
template <int LAST>
__global__ __launch_bounds__(256, 2) void k_mlp(
    const ushort_t* __restrict__ zhi, const ushort_t* __restrict__ zlo,
    const short* __restrict__ W1h, const short* __restrict__ W1l,
    const short* __restrict__ W2h, const short* __restrict__ W2l,
    const float* __restrict__ b1, const float* __restrict__ b2,
    const float* __restrict__ lng, const float* __restrict__ lnb,
    const ushort_t* __restrict__ hbin, const ushort_t* __restrict__ hbprev1,
    ushort_t* __restrict__ hbout, const float* __restrict__ pg,
    const float* __restrict__ pbv, ushort_t* __restrict__ zohi,
    ushort_t* __restrict__ zolo) {
  int lane = threadIdx.x & 63;
  int wid = threadIdx.x >> 6;
  int m = lane & 15;
  int q = lane >> 4;
  int n0 = blockIdx.x * 128 + wid * 32 + m;
  int valid[2];
  size_t base[2];
#pragma unroll
  for (int tt = 0; tt < 2; tt++) {
    int node = n0 + tt * 16;
    valid[tt] = node < NN;
    base[tt] = (size_t)(valid[tt] ? node : (NN - 1)) * DD;
  }

  // z fragments (B-operand of GEMM1'), 2 tiles x 4 k-groups
  bf16x8 zh[2][4], zl[2][4];
#pragma unroll
  for (int tt = 0; tt < 2; tt++) {
    const bf16x8* Zh = (const bf16x8*)(zhi + base[tt]);
    const bf16x8* Zl = (const bf16x8*)(zlo + base[tt]);
#pragma unroll
    for (int kk = 0; kk < 4; kk++) {
      zh[tt][kk] = Zh[kk * 4 + q];
      zl[tt][kk] = Zl[kk * 4 + q];
    }
  }

  // ---- GEMM1': A = W1^T frags (shared by both tiles), B = z frags
  const bf16x8* W1hp = (const bf16x8*)W1h;
  const bf16x8* W1lp = (const bf16x8*)W1l;
  f32x4 a1[2][8];
#pragma unroll
  for (int tt = 0; tt < 2; tt++)
#pragma unroll
    for (int t = 0; t < 8; t++) a1[tt][t] = (f32x4){0.f, 0.f, 0.f, 0.f};
#pragma unroll
  for (int kk = 0; kk < 4; kk++) {
    bf16x8 wh[8], wl[8];
#pragma unroll
    for (int t = 0; t < 8; t++) {
      wh[t] = W1hp[(t * 4 + kk) * 64 + lane];
      wl[t] = W1lp[(t * 4 + kk) * 64 + lane];
    }
#pragma unroll
    for (int t = 0; t < 8; t++) {
#pragma unroll
      for (int tt = 0; tt < 2; tt++) {
        a1[tt][t] = __builtin_amdgcn_mfma_f32_16x16x32_bf16(wh[t], zh[tt][kk], a1[tt][t], 0, 0, 0);
        a1[tt][t] = __builtin_amdgcn_mfma_f32_16x16x32_bf16(wl[t], zh[tt][kk], a1[tt][t], 0, 0, 0);
        a1[tt][t] = __builtin_amdgcn_mfma_f32_16x16x32_bf16(wh[t], zl[tt][kk], a1[tt][t], 0, 0, 0);
      }
    }
  }

  // ---- bias + relu + split-bf16, assembled directly into GEMM2 B-frags
  bf16x8 th[2][4], tl[2][4];
#pragma unroll
  for (int t = 0; t < 8; t++) {
    float4 bb = *(const float4*)(b1 + t * 16 + q * 4);
    float bbr[4] = {bb.x, bb.y, bb.z, bb.w};
#pragma unroll
    for (int tt = 0; tt < 2; tt++) {
#pragma unroll
      for (int r = 0; r < 4; r++) {
        float v = fmaxf(a1[tt][t][r] + bbr[r], 0.f);
        short hv = f2bf(v);
        short lv = f2bf(v - bf2f(hv));
        th[tt][t >> 1][(t & 1) * 4 + r] = hv;
        tl[tt][t >> 1][(t & 1) * 4 + r] = lv;
      }
    }
  }

  // residual loads (fp16) issued here so latency hides under GEMM2's MFMAs
  ushort4 hr4[2][8];
#pragma unroll
  for (int tt = 0; tt < 2; tt++)
#pragma unroll
    for (int t = 0; t < 8; t++)
      hr4[tt][t] = *(const ushort4*)(hbin + base[tt] + t * 16 + q * 4);

  // ---- GEMM2': A = k-permuted W2^T frags (shared), B = th/tl
  const bf16x8* W2hp = (const bf16x8*)W2h;
  const bf16x8* W2lp = (const bf16x8*)W2l;
  f32x4 a2[2][8];
#pragma unroll
  for (int tt = 0; tt < 2; tt++)
#pragma unroll
    for (int t = 0; t < 8; t++) a2[tt][t] = (f32x4){0.f, 0.f, 0.f, 0.f};
#pragma unroll
  for (int g = 0; g < 4; g++) {
    bf16x8 wh[8], wl[8];
#pragma unroll
    for (int t = 0; t < 8; t++) {
      wh[t] = W2hp[(t * 4 + g) * 64 + lane];
      wl[t] = W2lp[(t * 4 + g) * 64 + lane];
    }
#pragma unroll
    for (int t = 0; t < 8; t++) {
#pragma unroll
      for (int tt = 0; tt < 2; tt++) {
        a2[tt][t] = __builtin_amdgcn_mfma_f32_16x16x32_bf16(wh[t], th[tt][g], a2[tt][t], 0, 0, 0);
        a2[tt][t] = __builtin_amdgcn_mfma_f32_16x16x32_bf16(wl[t], th[tt][g], a2[tt][t], 0, 0, 0);
        a2[tt][t] = __builtin_amdgcn_mfma_f32_16x16x32_bf16(wh[t], tl[tt][g], a2[tt][t], 0, 0, 0);
      }
    }
  }

  // ---- epilogue, one tile at a time (per-node; lane holds dims 16t+4q+r)
#pragma unroll
  for (int tt = 0; tt < 2; tt++) {
    float s = 0.f, qs = 0.f;
#pragma unroll
    for (int t = 0; t < 8; t++) {
      float4 bb = *(const float4*)(b2 + t * 16 + q * 4);
      float bbr[4] = {bb.x, bb.y, bb.z, bb.w};
#pragma unroll
      for (int r = 0; r < 4; r++) {
        float u = a2[tt][t][r] + bbr[r];
        a2[tt][t][r] = u;
        s += u;
        qs += u * u;
      }
    }
    s += __shfl_xor(s, 16, 64);
    s += __shfl_xor(s, 32, 64);
    qs += __shfl_xor(qs, 16, 64);
    qs += __shfl_xor(qs, 32, 64);
    float mean = s * (1.0f / DD);
    float var = qs * (1.0f / DD) - mean * mean;
    float rstd = rsqrtf(var + LN_EPS);

    if (!LAST) {
#pragma unroll
      for (int t = 0; t < 8; t++) {
        float4 gg4 = *(const float4*)(lng + t * 16 + q * 4);
        float4 nb4 = *(const float4*)(lnb + t * 16 + q * 4);
        float ggr[4] = {gg4.x, gg4.y, gg4.z, gg4.w};
        float nbr[4] = {nb4.x, nb4.y, nb4.z, nb4.w};
        float hr[4] = {h2f(hr4[tt][t].x), h2f(hr4[tt][t].y), h2f(hr4[tt][t].z),
                       h2f(hr4[tt][t].w)};
        float o[4];
#pragma unroll
        for (int r = 0; r < 4; r++) {
          float z = (a2[tt][t][r] - mean) * rstd * ggr[r] + nbr[r];
          o[r] = gelu_fast(z) + hr[r];
        }
        if (valid[tt]) {
          ushort4 us;
          us.x = f2h(o[0]);
          us.y = f2h(o[1]);
          us.z = f2h(o[2]);
          us.w = f2h(o[3]);
          *(ushort4*)(hbout + base[tt] + t * 16 + q * 4) = us;
        }
      }
    } else {
      // hsum = (h1 + h2) + h3 in registers -> final pre-LN -> split bf16 z
      float w[8][4];
      float s2 = 0.f, q2 = 0.f;
#pragma unroll
      for (int t = 0; t < 8; t++) {
        float4 gg4 = *(const float4*)(lng + t * 16 + q * 4);
        float4 nb4 = *(const float4*)(lnb + t * 16 + q * 4);
        ushort4 hp4 = *(const ushort4*)(hbprev1 + base[tt] + t * 16 + q * 4);
        float ggr[4] = {gg4.x, gg4.y, gg4.z, gg4.w};
        float nbr[4] = {nb4.x, nb4.y, nb4.z, nb4.w};
        float hr[4] = {h2f(hr4[tt][t].x), h2f(hr4[tt][t].y), h2f(hr4[tt][t].z),
                       h2f(hr4[tt][t].w)};
        float pr[4] = {h2f(hp4.x), h2f(hp4.y), h2f(hp4.z), h2f(hp4.w)};
#pragma unroll
        for (int r = 0; r < 4; r++) {
          float z = (a2[tt][t][r] - mean) * rstd * ggr[r] + nbr[r];
          float o = gelu_fast(z) + hr[r];  // h3
          float wv = (pr[r] + hr[r]) + o;
          w[t][r] = wv;
          s2 += wv;
          q2 += wv * wv;
        }
      }
      s2 += __shfl_xor(s2, 16, 64);
      s2 += __shfl_xor(s2, 32, 64);
      q2 += __shfl_xor(q2, 16, 64);
      q2 += __shfl_xor(q2, 32, 64);
      float mean2 = s2 * (1.0f / DD);
      float var2 = q2 * (1.0f / DD) - mean2 * mean2;
      float rstd2 = rsqrtf(var2 + LN_EPS);
#pragma unroll
      for (int t = 0; t < 8; t++) {
        float4 pg4 = *(const float4*)(pg + t * 16 + q * 4);
        float4 pb4 = *(const float4*)(pbv + t * 16 + q * 4);
        float pgr[4] = {pg4.x, pg4.y, pg4.z, pg4.w};
        float pbr[4] = {pb4.x, pb4.y, pb4.z, pb4.w};
        short4 sh, sl;
        float v0 = (w[t][0] - mean2) * rstd2 * pgr[0] + pbr[0];
        float v1 = (w[t][1] - mean2) * rstd2 * pgr[1] + pbr[1];
        float v2 = (w[t][2] - mean2) * rstd2 * pgr[2] + pbr[2];
        float v3 = (w[t][3] - mean2) * rstd2 * pgr[3] + pbr[3];
        sh.x = f2bf(v0);
        sh.y = f2bf(v1);
        sh.z = f2bf(v2);
        sh.w = f2bf(v3);
        sl.x = f2bf(v0 - bf2f(sh.x));
        sl.y = f2bf(v1 - bf2f(sh.y));
        sl.z = f2bf(v2 - bf2f(sh.z));
        sl.w = f2bf(v3 - bf2f(sh.w));
        if (valid[tt]) {
          *(short4*)(zohi + base[tt] + t * 16 + q * 4) = sh;
          *(short4*)(zolo + base[tt] + t * 16 + q * 4) = sl;
        }
      }
    }
  }
}

// ---------------- final GEMM: out = A*pW + pb, 2 node-tiles per wave ---------
__global__ __launch_bounds__(256, 2) void k_mm(const ushort_t* __restrict__ Ahi,
                                               const ushort_t* __restrict__ Alo,
                                               const short* __restrict__ Bhi,
                                               const short* __restrict__ Blo,
                                               const float* __restrict__ bias,
                                               float* __restrict__ out) {
  int lane = threadIdx.x & 63;
  int wid = threadIdx.x >> 6;
  int m = lane & 15;
  int q = lane >> 4;
  int n0 = blockIdx.x * 128 + wid * 32 + m;
  int valid[2];
  size_t base[2];
#pragma unroll
  for (int tt = 0; tt < 2; tt++) {
    int node = n0 + tt * 16;
    valid[tt] = node < NN;
    base[tt] = (size_t)(valid[tt] ? node : (NN - 1)) * DD;
  }
  bf16x8 zh[2][4], zl[2][4];
#pragma unroll
  for (int tt = 0; tt < 2; tt++) {
    const bf16x8* Zh = (const bf16x8*)(Ahi + base[tt]);
    const bf16x8* Zl = (const bf16x8*)(Alo + base[tt]);
#pragma unroll
    for (int kk = 0; kk < 4; kk++) {
      zh[tt][kk] = Zh[kk * 4 + q];
      zl[tt][kk] = Zl[kk * 4 + q];
    }
  }
  const bf16x8* Bh = (const bf16x8*)Bhi;
  const bf16x8* Bl = (const bf16x8*)Blo;
  f32x4 acc[2][8];
#pragma unroll
  for (int tt = 0; tt < 2; tt++)
#pragma unroll
    for (int t = 0; t < 8; t++) acc[tt][t] = (f32x4){0.f, 0.f, 0.f, 0.f};
#pragma unroll
  for (int kk = 0; kk < 4; kk++) {
    bf16x8 wh[8], wl[8];
#pragma unroll
    for (int t = 0; t < 8; t++) {
      wh[t] = Bh[(t * 4 + kk) * 64 + lane];
      wl[t] = Bl[(t * 4 + kk) * 64 + lane];
    }
#pragma unroll
    for (int t = 0; t < 8; t++) {
#pragma unroll
      for (int tt = 0; tt < 2; tt++) {
        acc[tt][t] = __builtin_amdgcn_mfma_f32_16x16x32_bf16(wh[t], zh[tt][kk], acc[tt][t], 0, 0, 0);
        acc[tt][t] = __builtin_amdgcn_mfma_f32_16x16x32_bf16(wl[t], zh[tt][kk], acc[tt][t], 0, 0, 0);
        acc[tt][t] = __builtin_amdgcn_mfma_f32_16x16x32_bf16(wh[t], zl[tt][kk], acc[tt][t], 0, 0, 0);
      }
    }
  }
#pragma unroll
  for (int tt = 0; tt < 2; tt++) {
    if (valid[tt]) {
#pragma unroll
      for (int t = 0; t < 8; t++) {
        float4 bb = *(const float4*)(bias + t * 16 + q * 4);
        float4 o4;
        o4.x = acc[tt][t][0] + bb.x;
        o4.y = acc[tt][t][1] + bb.y;
        o4.z = acc[tt][t][2] + bb.z;
        o4.w = acc[tt][t][3] + bb.w;
        *(float4*)(out + base[tt] + t * 16 + q * 4) = o4;
      }
    }
  }
}

extern "C" void kernel_launch(void* const* d_in, const int* in_sizes, int n_in, void* d_out,
                              int out_size, void* d_ws, size_t ws_size, hipStream_t stream) {
  (void)in_sizes;
  (void)n_in;
  (void)out_size;
  (void)ws_size;
  const float* x = (const float*)d_in[0];
  const int* ei = (const int*)d_in[1];
  const float* W1 = (const float*)d_in[2];
  const float* b1 = (const float*)d_in[3];
  const float* W2 = (const float*)d_in[4];
  const float* b2 = (const float*)d_in[5];
  const float* eps = (const float*)d_in[6];
  const float* lng = (const float*)d_in[7];
  const float* lnb = (const float*)d_in[8];
  const float* plg = (const float*)d_in[9];
  const float* plb = (const float*)d_in[10];
  const float* pW = (const float*)d_in[11];
  const float* pb = (const float*)d_in[12];
  float* out = (float*)d_out;

  char* ws = (char*)d_ws;
  ushort_t* hb0 = (ushort_t*)ws;
  ws += (size_t)NN * DD * 2;
  ushort_t* hb1 = (ushort_t*)ws;
  ws += (size_t)NN * DD * 2;
  ushort_t* hb2 = (ushort_t*)ws;
  ws += (size_t)NN * DD * 2;
  ushort_t* zhi = (ushort_t*)ws;
  ws += (size_t)NN * DD * 2;
  ushort_t* zlo = (ushort_t*)ws;
  ws += (size_t)NN * DD * 2;
  short* wphi = (short*)ws;
  ws += (size_t)7 * 16384 * 2;
  short* wplo = (short*)ws;
  ws += (size_t)7 * 16384 * 2;
  int* deg = (int*)ws;
  ws += (size_t)NN * 4;
  int* rowst = (int*)ws;
  ws += (size_t)(NN + 1) * 4 + 60;
  int* bsum = (int*)ws;
  ws += 512;
  int* csr = (int*)ws;
  ws += (size_t)NE * 4;

  const int* srcv = ei;
  const int* dstv = ei + NE;

  hipMemsetAsync(deg, 0, (size_t)NN * 4, stream);
  k_count<<<4096, 256, 0, stream>>>(dstv, deg);
  k_block_sums<<<98, 256, 0, stream>>>(deg, bsum);
  k_scan_sums<<<1, 128, 0, stream>>>(bsum, 98);
  k_scan_write<<<98, 256, 0, stream>>>(deg, bsum, rowst);
  hipMemsetAsync(deg, 0, (size_t)NN * 4, stream);  // reuse as cursor
  k_fill<<<4096, 256, 0, stream>>>(srcv, dstv, rowst, deg, csr);
  k_pack<<<448, 256, 0, stream>>>(W1, W2, pW, wphi, wplo);
  k_cast<<<(NN * DD / 4 + 255) / 256, 256, 0, stream>>>(x, hb0);

  int mlp_grid = (NN + 127) / 128;  // 782, 4 waves/block, 32 nodes/wave
  ushort_t* hbs[NL + 1] = {hb0, hb1, hb2, nullptr};
  for (int l = 0; l < NL; l++) {
    k_gather<<<NN / 4, 256, 0, stream>>>(hbs[l], rowst, csr, eps, l, (unsigned*)zhi,
                                         (unsigned*)zlo);
    if (l < NL - 1) {
      k_mlp<0><<<mlp_grid, 256, 0, stream>>>(
          zhi, zlo, wphi + (size_t)(2 * l) * 16384, wplo + (size_t)(2 * l) * 16384,
          wphi + (size_t)(2 * l + 1) * 16384, wplo + (size_t)(2 * l + 1) * 16384, b1 + l * DD,
          b2 + l * DD, lng + l * DD, lnb + l * DD, hbs[l], hb1, hbs[l + 1], plg, plb, zhi,
          zlo);
    } else {
      k_mlp<1><<<mlp_grid, 256, 0, stream>>>(
          zhi, zlo, wphi + (size_t)(2 * l) * 16384, wplo + (size_t)(2 * l) * 16384,
          wphi + (size_t)(2 * l + 1) * 16384, wplo + (size_t)(2 * l + 1) * 16384, b1 + l * DD,
          b2 + l * DD, lng + l * DD, lnb + l * DD, hbs[l], hb1, nullptr, plg, plb, zhi, zlo);
    }
  }
  k_mm<<<mlp_grid, 256, 0, stream>>>(zhi, zlo, wphi + (size_t)6 * 16384,
                                     wplo + (size_t)6 * 16384, pb, out);
}

// Round 9
// 623.027 us; speedup vs baseline: 1.2021x; 1.2021x over previous
//
#include <hip/hip_runtime.h>
#include <math.h>

#define NN 100000
#define NE 1600000
#define DD 128
#define NL 3
#define LN_EPS 1e-5f
#define NRANGE 8
#define RSZ (NN / NRANGE)  // 12500

typedef __attribute__((ext_vector_type(8))) _Float16 f16x8;
typedef __attribute__((ext_vector_type(4))) float f32x4;
typedef unsigned short ushort_t;

__device__ __forceinline__ unsigned short f2h(float f) {
  _Float16 h = (_Float16)f;
  unsigned short u;
  __builtin_memcpy(&u, &h, 2);
  return u;
}
__device__ __forceinline__ float h2f(unsigned short u) {
  _Float16 h;
  __builtin_memcpy(&h, &u, 2);
  return (float)h;
}
// gelu with fast erf (A&S 7.1.26, |err|<1.5e-7 -- far below tolerance)
__device__ __forceinline__ float gelu_fast(float x) {
  float xs = x * 0.7071067811865476f;
  float ax = fabsf(xs);
  float t = __builtin_amdgcn_rcpf(fmaf(0.3275911f, ax, 1.0f));
  float p = fmaf(t, 1.061405429f, -1.453152027f);
  p = fmaf(t, p, 1.421413741f);
  p = fmaf(t, p, -0.284496736f);
  p = fmaf(t, p, 0.254829592f);
  p = p * t;
  float e = __expf(-ax * ax);
  float er = fmaf(-p, e, 1.0f);
  er = copysignf(er, xs);
  return 0.5f * x * (1.0f + er);
}

// ---------------- CSR build (XCD-ranged scatters) ----------------
__global__ __launch_bounds__(256) void k_count(const int* __restrict__ dst,
                                               int* __restrict__ deg) {
  int range = blockIdx.x & (NRANGE - 1);
  int lo = range * RSZ;
  int hi = lo + RSZ;  // NN divisible by 8
  int nblk = gridDim.x >> 3;
  int bid = blockIdx.x >> 3;
  for (int e = bid * 256 + threadIdx.x; e < NE; e += nblk * 256) {
    int d = dst[e];
    if (d >= lo && d < hi) atomicAdd(&deg[d], 1);
  }
}

__global__ void k_block_sums(const int* __restrict__ deg, int* __restrict__ bsum) {
  __shared__ int sh[256];
  int t = threadIdx.x;
  int base = blockIdx.x * 1024;
  int s = 0;
#pragma unroll
  for (int j = 0; j < 4; j++) {
    int idx = base + t * 4 + j;
    if (idx < NN) s += deg[idx];
  }
  sh[t] = s;
  __syncthreads();
  for (int off = 128; off > 0; off >>= 1) {
    if (t < off) sh[t] += sh[t + off];
    __syncthreads();
  }
  if (t == 0) bsum[blockIdx.x] = sh[0];
}

__global__ void k_scan_sums(int* __restrict__ bsum, int nb) {
  __shared__ int sh[128];
  int t = threadIdx.x;
  int v = (t < nb) ? bsum[t] : 0;
  int acc = v;
  sh[t] = v;
  __syncthreads();
  for (int off = 1; off < 128; off <<= 1) {
    int o = (t >= off) ? sh[t - off] : 0;
    __syncthreads();
    acc += o;
    sh[t] = acc;
    __syncthreads();
  }
  if (t < nb) bsum[t] = acc - v;  // exclusive
}

__global__ void k_scan_write(const int* __restrict__ deg, const int* __restrict__ bsum,
                             int* __restrict__ rowstart) {
  __shared__ int sh[256];
  int t = threadIdx.x;
  int base = blockIdx.x * 1024;
  int idx0 = base + t * 4;
  int v[4];
  int s = 0;
#pragma unroll
  for (int j = 0; j < 4; j++) {
    int idx = idx0 + j;
    v[j] = (idx < NN) ? deg[idx] : 0;
    s += v[j];
  }
  int acc = s;
  sh[t] = s;
  __syncthreads();
  for (int off = 1; off < 256; off <<= 1) {
    int o = (t >= off) ? sh[t - off] : 0;
    __syncthreads();
    acc += o;
    sh[t] = acc;
    __syncthreads();
  }
  int excl = acc - s + bsum[blockIdx.x];
#pragma unroll
  for (int j = 0; j < 4; j++) {
    int idx = idx0 + j;
    if (idx < NN) rowstart[idx] = excl;
    excl += v[j];
  }
  if (blockIdx.x == 0 && t == 0) rowstart[NN] = NE;
}

__global__ __launch_bounds__(256) void k_fill(const int* __restrict__ src,
                                              const int* __restrict__ dst,
                                              const int* __restrict__ rowstart,
                                              int* __restrict__ cursor,
                                              int* __restrict__ csr) {
  int range = blockIdx.x & (NRANGE - 1);
  int lo = range * RSZ;
  int hi = lo + RSZ;
  int nblk = gridDim.x >> 3;
  int bid = blockIdx.x >> 3;
  for (int e = bid * 256 + threadIdx.x; e < NE; e += nblk * 256) {
    int d = dst[e];
    if (d >= lo && d < hi) {
      int p = atomicAdd(&cursor[d], 1);
      csr[rowstart[d] + p] = src[e];
    }
  }
}

// ---------------- W pre-pack into MFMA A-of-W^T fragment order (fp16) --------
// W1, pW: k = 32kk + 8q + j (natural order).
// W2:     k = 32kk + 16(j>>2) + 4q + (j&3) -- permutation that makes the
//         GEMM2 B-fragment equal the GEMM1' accumulator layout (no LDS xpose).
__global__ void k_pack(const float* __restrict__ W1, const float* __restrict__ W2,
                       const float* __restrict__ pW, ushort_t* __restrict__ wp) {
  int id = blockIdx.x * 256 + threadIdx.x;  // 7*16384
  int mtx = id >> 14;                       // 0..6
  int r = id & 16383;
  const float* src;
  int perm = 0;
  if (mtx == 6) {
    src = pW;  // natural pack: k_mm consumes memory-layout B-frags
  } else {
    int layer = mtx >> 1;
    if (mtx & 1) {
      src = W2 + layer * 16384;
      perm = 1;
    } else {
      src = W1 + layer * 16384;
    }
  }
  int j = r & 7;
  int l = (r >> 3) & 63;
  int kk = (r >> 9) & 3;
  int t = r >> 11;
  int qq = (l >> 4) & 3;
  int k = perm ? (kk * 32 + ((j >> 2) << 4) + (qq << 2) + (j & 3))
               : (kk * 32 + (qq << 3) + j);
  int n = t * 16 + (l & 15);
  wp[id] = f2h(src[k * DD + n]);
}

// ---------------- x -> fp16 h0 ----------------
__global__ void k_cast(const float* __restrict__ x, ushort_t* __restrict__ hb) {
  int i = blockIdx.x * 256 + threadIdx.x;  // over NN*DD/4
  if (i < NN * DD / 4) {
    float4 v = ((const float4*)x)[i];
    ushort4 o;
    o.x = f2h(v.x);
    o.y = f2h(v.y);
    o.z = f2h(v.z);
    o.w = f2h(v.w);
    ((ushort4*)hb)[i] = o;
  }
}

// ---- gather: z = (1+eps)*hb[n] + sum_{incoming} hb[src] (fp16) -> fp16 z ----
__global__ __launch_bounds__(256) void k_gather(const ushort_t* __restrict__ hb,
                                                const int* __restrict__ rowstart,
                                                const int* __restrict__ csr,
                                                const float* __restrict__ eps, int layer,
                                                unsigned* __restrict__ z) {
  int n = blockIdx.x * 4 + (threadIdx.x >> 6);
  int t = threadIdx.x & 63;  // column pair 0..63
  const unsigned* hb2 = (const unsigned*)hb;
  unsigned sv = hb2[(size_t)n * 64 + t];
  float e1 = 1.0f + eps[layer];
  float a0 = e1 * h2f((ushort_t)(sv & 0xffffu));
  float a1 = e1 * h2f((ushort_t)(sv >> 16));
  float b0 = 0.f, b1 = 0.f, c0 = 0.f, c1 = 0.f, d0 = 0.f, d1 = 0.f;
  int s = rowstart[n], e = rowstart[n + 1];
  int k = s;
  for (; k + 3 < e; k += 4) {
    int n0 = csr[k], n1 = csr[k + 1], n2 = csr[k + 2], n3 = csr[k + 3];
    unsigned v0 = hb2[(size_t)n0 * 64 + t];
    unsigned v1 = hb2[(size_t)n1 * 64 + t];
    unsigned v2 = hb2[(size_t)n2 * 64 + t];
    unsigned v3 = hb2[(size_t)n3 * 64 + t];
    a0 += h2f((ushort_t)(v0 & 0xffffu));
    a1 += h2f((ushort_t)(v0 >> 16));
    b0 += h2f((ushort_t)(v1 & 0xffffu));
    b1 += h2f((ushort_t)(v1 >> 16));
    c0 += h2f((ushort_t)(v2 & 0xffffu));
    c1 += h2f((ushort_t)(v2 >> 16));
    d0 += h2f((ushort_t)(v3 & 0xffffu));
    d1 += h2f((ushort_t)(v3 >> 16));
  }
  for (; k < e; k++) {
    unsigned v = hb2[(size_t)csr[k] * 64 + t];
    a0 += h2f((ushort_t)(v & 0xffffu));
    a1 += h2f((ushort_t)(v >> 16));
  }
  a0 += (b0 + c0) + d0;
  a1 += (b1 + c1) + d1;
  z[(size_t)n * 64 + t] = (unsigned)f2h(a0) | ((unsigned)f2h(a1) << 16);
}

// ------- fused MLP: swapped-operand, LDS-free, fp16 single-MFMA --------------
// Per wave: 64 weight-fragment loads + 64 MFMAs (was 128 + 192 split-bf16).
// fp16 (11-bit mantissa) GEMM noise ~5e-4/output -- far below tolerance.
template <int LAST>
__global__ __launch_bounds__(256, 3) void k_mlp(
    const ushort_t* __restrict__ z, const ushort_t* __restrict__ W1p,
    const ushort_t* __restrict__ W2p, const float* __restrict__ b1,
    const float* __restrict__ b2, const float* __restrict__ lng,
    const float* __restrict__ lnb, const ushort_t* __restrict__ hbin,
    const ushort_t* __restrict__ hbprev1, ushort_t* __restrict__ hbout,
    const float* __restrict__ pg, const float* __restrict__ pbv,
    ushort_t* __restrict__ zo) {
  int lane = threadIdx.x & 63;
  int wid = threadIdx.x >> 6;
  int m = lane & 15;
  int q = lane >> 4;
  int node = blockIdx.x * 64 + wid * 16 + m;
  int valid = node < NN;
  int node_c = valid ? node : (NN - 1);
  size_t base = (size_t)node_c * DD;

  // z fragments (B-operand of GEMM1'), 4 k-groups
  const f16x8* Zf = (const f16x8*)(z + base);
  f16x8 zf[4];
#pragma unroll
  for (int kk = 0; kk < 4; kk++) zf[kk] = Zf[kk * 4 + q];

  // ---- GEMM1': A = W1^T frags, B = z frags. Batched loads per kk-group.
  const f16x8* W1f = (const f16x8*)W1p;
  f32x4 a1[8];
#pragma unroll
  for (int t = 0; t < 8; t++) a1[t] = (f32x4){0.f, 0.f, 0.f, 0.f};
#pragma unroll
  for (int kk = 0; kk < 4; kk++) {
    f16x8 wf[8];
#pragma unroll
    for (int t = 0; t < 8; t++) wf[t] = W1f[(t * 4 + kk) * 64 + lane];
#pragma unroll
    for (int t = 0; t < 8; t++)
      a1[t] = __builtin_amdgcn_mfma_f32_16x16x32_f16(wf[t], zf[kk], a1[t], 0, 0, 0);
  }

  // ---- bias + relu -> fp16, assembled directly into GEMM2 B-frags
  f16x8 tf[4];
#pragma unroll
  for (int t = 0; t < 8; t++) {
    float4 bb = *(const float4*)(b1 + t * 16 + q * 4);
    float bbr[4] = {bb.x, bb.y, bb.z, bb.w};
#pragma unroll
    for (int r = 0; r < 4; r++) {
      float v = fmaxf(a1[t][r] + bbr[r], 0.f);
      tf[t >> 1][(t & 1) * 4 + r] = (_Float16)v;
    }
  }

  // residual loads (fp16) issued here so latency hides under GEMM2's MFMAs
  ushort4 hr4[8];
#pragma unroll
  for (int t = 0; t < 8; t++) hr4[t] = *(const ushort4*)(hbin + base + t * 16 + q * 4);

  // ---- GEMM2': A = k-permuted W2^T frags, B = tf. Batched loads.
  const f16x8* W2f = (const f16x8*)W2p;
  f32x4 a2[8];
#pragma unroll
  for (int t = 0; t < 8; t++) a2[t] = (f32x4){0.f, 0.f, 0.f, 0.f};
#pragma unroll
  for (int g = 0; g < 4; g++) {
    f16x8 wf[8];
#pragma unroll
    for (int t = 0; t < 8; t++) wf[t] = W2f[(t * 4 + g) * 64 + lane];
#pragma unroll
    for (int t = 0; t < 8; t++)
      a2[t] = __builtin_amdgcn_mfma_f32_16x16x32_f16(wf[t], tf[g], a2[t], 0, 0, 0);
  }

  // ---- epilogue (per-node; lane holds dims 16t+4q+r of node)
  float s = 0.f, qs = 0.f;
#pragma unroll
  for (int t = 0; t < 8; t++) {
    float4 bb = *(const float4*)(b2 + t * 16 + q * 4);
    float bbr[4] = {bb.x, bb.y, bb.z, bb.w};
#pragma unroll
    for (int r = 0; r < 4; r++) {
      float u = a2[t][r] + bbr[r];
      a2[t][r] = u;
      s += u;
      qs += u * u;
    }
  }
  s += __shfl_xor(s, 16, 64);
  s += __shfl_xor(s, 32, 64);
  qs += __shfl_xor(qs, 16, 64);
  qs += __shfl_xor(qs, 32, 64);
  float mean = s * (1.0f / DD);
  float var = qs * (1.0f / DD) - mean * mean;
  float rstd = rsqrtf(var + LN_EPS);

  if (!LAST) {
#pragma unroll
    for (int t = 0; t < 8; t++) {
      float4 gg4 = *(const float4*)(lng + t * 16 + q * 4);
      float4 nb4 = *(const float4*)(lnb + t * 16 + q * 4);
      float ggr[4] = {gg4.x, gg4.y, gg4.z, gg4.w};
      float nbr[4] = {nb4.x, nb4.y, nb4.z, nb4.w};
      float hr[4] = {h2f(hr4[t].x), h2f(hr4[t].y), h2f(hr4[t].z), h2f(hr4[t].w)};
      float o[4];
#pragma unroll
      for (int r = 0; r < 4; r++) {
        float zz = (a2[t][r] - mean) * rstd * ggr[r] + nbr[r];
        o[r] = gelu_fast(zz) + hr[r];
      }
      if (valid) {
        ushort4 us;
        us.x = f2h(o[0]);
        us.y = f2h(o[1]);
        us.z = f2h(o[2]);
        us.w = f2h(o[3]);
        *(ushort4*)(hbout + base + t * 16 + q * 4) = us;
      }
    }
  } else {
    // hsum = (h1 + h2) + h3 in registers -> final pre-LN -> fp16 zo
    float w[8][4];
    float s2 = 0.f, q2 = 0.f;
#pragma unroll
    for (int t = 0; t < 8; t++) {
      float4 gg4 = *(const float4*)(lng + t * 16 + q * 4);
      float4 nb4 = *(const float4*)(lnb + t * 16 + q * 4);
      ushort4 hp4 = *(const ushort4*)(hbprev1 + base + t * 16 + q * 4);
      float ggr[4] = {gg4.x, gg4.y, gg4.z, gg4.w};
      float nbr[4] = {nb4.x, nb4.y, nb4.z, nb4.w};
      float hr[4] = {h2f(hr4[t].x), h2f(hr4[t].y), h2f(hr4[t].z), h2f(hr4[t].w)};
      float pr[4] = {h2f(hp4.x), h2f(hp4.y), h2f(hp4.z), h2f(hp4.w)};
#pragma unroll
      for (int r = 0; r < 4; r++) {
        float zz = (a2[t][r] - mean) * rstd * ggr[r] + nbr[r];
        float o = gelu_fast(zz) + hr[r];  // h3
        float wv = (pr[r] + hr[r]) + o;
        w[t][r] = wv;
        s2 += wv;
        q2 += wv * wv;
      }
    }
    s2 += __shfl_xor(s2, 16, 64);
    s2 += __shfl_xor(s2, 32, 64);
    q2 += __shfl_xor(q2, 16, 64);
    q2 += __shfl_xor(q2, 32, 64);
    float mean2 = s2 * (1.0f / DD);
    float var2 = q2 * (1.0f / DD) - mean2 * mean2;
    float rstd2 = rsqrtf(var2 + LN_EPS);
#pragma unroll
    for (int t = 0; t < 8; t++) {
      float4 pg4 = *(const float4*)(pg + t * 16 + q * 4);
      float4 pb4 = *(const float4*)(pbv + t * 16 + q * 4);
      float pgr[4] = {pg4.x, pg4.y, pg4.z, pg4.w};
      float pbr[4] = {pb4.x, pb4.y, pb4.z, pb4.w};
      float v0 = (w[t][0] - mean2) * rstd2 * pgr[0] + pbr[0];
      float v1 = (w[t][1] - mean2) * rstd2 * pgr[1] + pbr[1];
      float v2 = (w[t][2] - mean2) * rstd2 * pgr[2] + pbr[2];
      float v3 = (w[t][3] - mean2) * rstd2 * pgr[3] + pbr[3];
      if (valid) {
        ushort4 us;
        us.x = f2h(v0);
        us.y = f2h(v1);
        us.z = f2h(v2);
        us.w = f2h(v3);
        *(ushort4*)(zo + base + t * 16 + q * 4) = us;
      }
    }
  }
}

// ---------------- final GEMM: out = A*pW + pb, fp16 single-MFMA --------------
__global__ __launch_bounds__(256, 3) void k_mm(const ushort_t* __restrict__ zo,
                                               const ushort_t* __restrict__ Bp,
                                               const float* __restrict__ bias,
                                               float* __restrict__ out) {
  int lane = threadIdx.x & 63;
  int wid = threadIdx.x >> 6;
  int m = lane & 15;
  int q = lane >> 4;
  int node = blockIdx.x * 64 + wid * 16 + m;
  int valid = node < NN;
  int node_c = valid ? node : (NN - 1);
  size_t base = (size_t)node_c * DD;
  const f16x8* Zf = (const f16x8*)(zo + base);
  f16x8 zf[4];
#pragma unroll
  for (int kk = 0; kk < 4; kk++) zf[kk] = Zf[kk * 4 + q];
  const f16x8* Bf = (const f16x8*)Bp;
  f32x4 acc[8];
#pragma unroll
  for (int t = 0; t < 8; t++) acc[t] = (f32x4){0.f, 0.f, 0.f, 0.f};
#pragma unroll
  for (int kk = 0; kk < 4; kk++) {
    f16x8 wf[8];
#pragma unroll
    for (int t = 0; t < 8; t++) wf[t] = Bf[(t * 4 + kk) * 64 + lane];
#pragma unroll
    for (int t = 0; t < 8; t++)
      acc[t] = __builtin_amdgcn_mfma_f32_16x16x32_f16(wf[t], zf[kk], acc[t], 0, 0, 0);
  }
  if (valid) {
#pragma unroll
    for (int t = 0; t < 8; t++) {
      float4 bb = *(const float4*)(bias + t * 16 + q * 4);
      float4 o4;
      o4.x = acc[t][0] + bb.x;
      o4.y = acc[t][1] + bb.y;
      o4.z = acc[t][2] + bb.z;
      o4.w = acc[t][3] + bb.w;
      *(float4*)(out + base + t * 16 + q * 4) = o4;
    }
  }
}

extern "C" void kernel_launch(void* const* d_in, const int* in_sizes, int n_in, void* d_out,
                              int out_size, void* d_ws, size_t ws_size, hipStream_t stream) {
  (void)in_sizes;
  (void)n_in;
  (void)out_size;
  (void)ws_size;
  const float* x = (const float*)d_in[0];
  const int* ei = (const int*)d_in[1];
  const float* W1 = (const float*)d_in[2];
  const float* b1 = (const float*)d_in[3];
  const float* W2 = (const float*)d_in[4];
  const float* b2 = (const float*)d_in[5];
  const float* eps = (const float*)d_in[6];
  const float* lng = (const float*)d_in[7];
  const float* lnb = (const float*)d_in[8];
  const float* plg = (const float*)d_in[9];
  const float* plb = (const float*)d_in[10];
  const float* pW = (const float*)d_in[11];
  const float* pb = (const float*)d_in[12];
  float* out = (float*)d_out;

  char* ws = (char*)d_ws;
  ushort_t* hb0 = (ushort_t*)ws;
  ws += (size_t)NN * DD * 2;
  ushort_t* hb1 = (ushort_t*)ws;
  ws += (size_t)NN * DD * 2;
  ushort_t* hb2 = (ushort_t*)ws;
  ws += (size_t)NN * DD * 2;
  ushort_t* z = (ushort_t*)ws;
  ws += (size_t)NN * DD * 2;
  ushort_t* zo = (ushort_t*)ws;
  ws += (size_t)NN * DD * 2;
  ushort_t* wp = (ushort_t*)ws;
  ws += (size_t)7 * 16384 * 2;
  int* deg = (int*)ws;
  ws += (size_t)NN * 4;
  int* rowst = (int*)ws;
  ws += (size_t)(NN + 1) * 4 + 60;
  int* bsum = (int*)ws;
  ws += 512;
  int* csr = (int*)ws;
  ws += (size_t)NE * 4;

  const int* srcv = ei;
  const int* dstv = ei + NE;

  hipMemsetAsync(deg, 0, (size_t)NN * 4, stream);
  k_count<<<4096, 256, 0, stream>>>(dstv, deg);
  k_block_sums<<<98, 256, 0, stream>>>(deg, bsum);
  k_scan_sums<<<1, 128, 0, stream>>>(bsum, 98);
  k_scan_write<<<98, 256, 0, stream>>>(deg, bsum, rowst);
  hipMemsetAsync(deg, 0, (size_t)NN * 4, stream);  // reuse as cursor
  k_fill<<<4096, 256, 0, stream>>>(srcv, dstv, rowst, deg, csr);
  k_pack<<<448, 256, 0, stream>>>(W1, W2, pW, wp);
  k_cast<<<(NN * DD / 4 + 255) / 256, 256, 0, stream>>>(x, hb0);

  int mlp_grid = (NN + 63) / 64;  // 1563, 4 waves/block, 16 nodes/wave
  ushort_t* hbs[NL + 1] = {hb0, hb1, hb2, nullptr};
  for (int l = 0; l < NL; l++) {
    k_gather<<<NN / 4, 256, 0, stream>>>(hbs[l], rowst, csr, eps, l, (unsigned*)z);
    if (l < NL - 1) {
      k_mlp<0><<<mlp_grid, 256, 0, stream>>>(
          z, wp + (size_t)(2 * l) * 16384, wp + (size_t)(2 * l + 1) * 16384, b1 + l * DD,
          b2 + l * DD, lng + l * DD, lnb + l * DD, hbs[l], hb1, hbs[l + 1], plg, plb, zo);
    } else {
      k_mlp<1><<<mlp_grid, 256, 0, stream>>>(
          z, wp + (size_t)(2 * l) * 16384, wp + (size_t)(2 * l + 1) * 16384, b1 + l * DD,
          b2 + l * DD, lng + l * DD, lnb + l * DD, hbs[l], hb1, hb0, plg, plb, zo);
    }
  }
  k_mm<<<mlp_grid, 256, 0, stream>>>(zo, wp + (size_t)6 * 16384, pb, out);
}

// Round 10
// 583.583 us; speedup vs baseline: 1.2834x; 1.0676x over previous
//
#include <hip/hip_runtime.h>
#include <math.h>

#define NN 100000
#define NE 1600000
#define DD 128
#define NL 3
#define LN_EPS 1e-5f
#define NRANGE 8
#define RSZ (NN / NRANGE)  // 12500

typedef __attribute__((ext_vector_type(8))) _Float16 f16x8;
typedef __attribute__((ext_vector_type(4))) float f32x4;
typedef unsigned short ushort_t;

__device__ __forceinline__ unsigned short f2h(float f) {
  _Float16 h = (_Float16)f;
  unsigned short u;
  __builtin_memcpy(&u, &h, 2);
  return u;
}
__device__ __forceinline__ float h2f(unsigned short u) {
  _Float16 h;
  __builtin_memcpy(&h, &u, 2);
  return (float)h;
}
// gelu with fast erf (A&S 7.1.26, |err|<1.5e-7 -- far below tolerance)
__device__ __forceinline__ float gelu_fast(float x) {
  float xs = x * 0.7071067811865476f;
  float ax = fabsf(xs);
  float t = __builtin_amdgcn_rcpf(fmaf(0.3275911f, ax, 1.0f));
  float p = fmaf(t, 1.061405429f, -1.453152027f);
  p = fmaf(t, p, 1.421413741f);
  p = fmaf(t, p, -0.284496736f);
  p = fmaf(t, p, 0.254829592f);
  p = p * t;
  float e = __expf(-ax * ax);
  float er = fmaf(-p, e, 1.0f);
  er = copysignf(er, xs);
  return 0.5f * x * (1.0f + er);
}

// ---------------- CSR build ----------------
// ONE atomic pass: k_count records each edge's slot (epos). k_fill then has
// ZERO atomics -- positions are unique by construction -- and stays XCD-ranged
// so its scatter stores merge in the local L2 before writeback.
__global__ __launch_bounds__(256) void k_count(const int* __restrict__ dst,
                                               int* __restrict__ deg,
                                               int* __restrict__ epos) {
  int e = blockIdx.x * blockDim.x + threadIdx.x;
  if (e < NE) epos[e] = atomicAdd(&deg[dst[e]], 1);
}

__global__ void k_block_sums(const int* __restrict__ deg, int* __restrict__ bsum) {
  __shared__ int sh[256];
  int t = threadIdx.x;
  int base = blockIdx.x * 1024;
  int s = 0;
#pragma unroll
  for (int j = 0; j < 4; j++) {
    int idx = base + t * 4 + j;
    if (idx < NN) s += deg[idx];
  }
  sh[t] = s;
  __syncthreads();
  for (int off = 128; off > 0; off >>= 1) {
    if (t < off) sh[t] += sh[t + off];
    __syncthreads();
  }
  if (t == 0) bsum[blockIdx.x] = sh[0];
}

__global__ void k_scan_sums(int* __restrict__ bsum, int nb) {
  __shared__ int sh[128];
  int t = threadIdx.x;
  int v = (t < nb) ? bsum[t] : 0;
  int acc = v;
  sh[t] = v;
  __syncthreads();
  for (int off = 1; off < 128; off <<= 1) {
    int o = (t >= off) ? sh[t - off] : 0;
    __syncthreads();
    acc += o;
    sh[t] = acc;
    __syncthreads();
  }
  if (t < nb) bsum[t] = acc - v;  // exclusive
}

__global__ void k_scan_write(const int* __restrict__ deg, const int* __restrict__ bsum,
                             int* __restrict__ rowstart) {
  __shared__ int sh[256];
  int t = threadIdx.x;
  int base = blockIdx.x * 1024;
  int idx0 = base + t * 4;
  int v[4];
  int s = 0;
#pragma unroll
  for (int j = 0; j < 4; j++) {
    int idx = idx0 + j;
    v[j] = (idx < NN) ? deg[idx] : 0;
    s += v[j];
  }
  int acc = s;
  sh[t] = s;
  __syncthreads();
  for (int off = 1; off < 256; off <<= 1) {
    int o = (t >= off) ? sh[t - off] : 0;
    __syncthreads();
    acc += o;
    sh[t] = acc;
    __syncthreads();
  }
  int excl = acc - s + bsum[blockIdx.x];
#pragma unroll
  for (int j = 0; j < 4; j++) {
    int idx = idx0 + j;
    if (idx < NN) rowstart[idx] = excl;
    excl += v[j];
  }
  if (blockIdx.x == 0 && t == 0) rowstart[NN] = NE;
}

__global__ __launch_bounds__(256) void k_fill(const int* __restrict__ src,
                                              const int* __restrict__ dst,
                                              const int* __restrict__ rowstart,
                                              const int* __restrict__ epos,
                                              int* __restrict__ csr) {
  int range = blockIdx.x & (NRANGE - 1);
  int lo = range * RSZ;
  int hi = lo + RSZ;
  int nblk = gridDim.x >> 3;
  int bid = blockIdx.x >> 3;
  for (int e = bid * 256 + threadIdx.x; e < NE; e += nblk * 256) {
    int d = dst[e];
    if (d >= lo && d < hi) {
      csr[rowstart[d] + epos[e]] = src[e];
    }
  }
}

// ---------------- W pre-pack into MFMA A-of-W^T fragment order (fp16) --------
// W1, pW: k = 32kk + 8q + j (natural order).
// W2:     k = 32kk + 16(j>>2) + 4q + (j&3) -- permutation that makes the
//         GEMM2 B-fragment equal the GEMM1' accumulator layout (no LDS xpose).
__global__ void k_pack(const float* __restrict__ W1, const float* __restrict__ W2,
                       const float* __restrict__ pW, ushort_t* __restrict__ wp) {
  int id = blockIdx.x * 256 + threadIdx.x;  // 7*16384
  int mtx = id >> 14;                       // 0..6
  int r = id & 16383;
  const float* src;
  int perm = 0;
  if (mtx == 6) {
    src = pW;  // natural pack: k_mm consumes memory-layout B-frags
  } else {
    int layer = mtx >> 1;
    if (mtx & 1) {
      src = W2 + layer * 16384;
      perm = 1;
    } else {
      src = W1 + layer * 16384;
    }
  }
  int j = r & 7;
  int l = (r >> 3) & 63;
  int kk = (r >> 9) & 3;
  int t = r >> 11;
  int qq = (l >> 4) & 3;
  int k = perm ? (kk * 32 + ((j >> 2) << 4) + (qq << 2) + (j & 3))
               : (kk * 32 + (qq << 3) + j);
  int n = t * 16 + (l & 15);
  wp[id] = f2h(src[k * DD + n]);
}

// ---------------- x -> fp16 h0 ----------------
__global__ void k_cast(const float* __restrict__ x, ushort_t* __restrict__ hb) {
  int i = blockIdx.x * 256 + threadIdx.x;  // over NN*DD/4
  if (i < NN * DD / 4) {
    float4 v = ((const float4*)x)[i];
    ushort4 o;
    o.x = f2h(v.x);
    o.y = f2h(v.y);
    o.z = f2h(v.z);
    o.w = f2h(v.w);
    ((ushort4*)hb)[i] = o;
  }
}

// ---- gather: z = (1+eps)*hb[n] + sum_{incoming} hb[src] (fp16) -> fp16 z ----
__global__ __launch_bounds__(256) void k_gather(const ushort_t* __restrict__ hb,
                                                const int* __restrict__ rowstart,
                                                const int* __restrict__ csr,
                                                const float* __restrict__ eps, int layer,
                                                unsigned* __restrict__ z) {
  int n = blockIdx.x * 4 + (threadIdx.x >> 6);
  int t = threadIdx.x & 63;  // column pair 0..63
  const unsigned* hb2 = (const unsigned*)hb;
  unsigned sv = hb2[(size_t)n * 64 + t];
  float e1 = 1.0f + eps[layer];
  float a0 = e1 * h2f((ushort_t)(sv & 0xffffu));
  float a1 = e1 * h2f((ushort_t)(sv >> 16));
  float b0 = 0.f, b1 = 0.f, c0 = 0.f, c1 = 0.f, d0 = 0.f, d1 = 0.f;
  int s = rowstart[n], e = rowstart[n + 1];
  int k = s;
  for (; k + 3 < e; k += 4) {
    int n0 = csr[k], n1 = csr[k + 1], n2 = csr[k + 2], n3 = csr[k + 3];
    unsigned v0 = hb2[(size_t)n0 * 64 + t];
    unsigned v1 = hb2[(size_t)n1 * 64 + t];
    unsigned v2 = hb2[(size_t)n2 * 64 + t];
    unsigned v3 = hb2[(size_t)n3 * 64 + t];
    a0 += h2f((ushort_t)(v0 & 0xffffu));
    a1 += h2f((ushort_t)(v0 >> 16));
    b0 += h2f((ushort_t)(v1 & 0xffffu));
    b1 += h2f((ushort_t)(v1 >> 16));
    c0 += h2f((ushort_t)(v2 & 0xffffu));
    c1 += h2f((ushort_t)(v2 >> 16));
    d0 += h2f((ushort_t)(v3 & 0xffffu));
    d1 += h2f((ushort_t)(v3 >> 16));
  }
  for (; k < e; k++) {
    unsigned v = hb2[(size_t)csr[k] * 64 + t];
    a0 += h2f((ushort_t)(v & 0xffffu));
    a1 += h2f((ushort_t)(v >> 16));
  }
  a0 += (b0 + c0) + d0;
  a1 += (b1 + c1) + d1;
  z[(size_t)n * 64 + t] = (unsigned)f2h(a0) | ((unsigned)f2h(a1) << 16);
}

// ------- fused MLP: swapped-operand, LDS-free, fp16 single-MFMA --------------
template <int LAST>
__global__ __launch_bounds__(256, 4) void k_mlp(
    const ushort_t* __restrict__ z, const ushort_t* __restrict__ W1p,
    const ushort_t* __restrict__ W2p, const float* __restrict__ b1,
    const float* __restrict__ b2, const float* __restrict__ lng,
    const float* __restrict__ lnb, const ushort_t* __restrict__ hbin,
    const ushort_t* __restrict__ hbprev1, ushort_t* __restrict__ hbout,
    const float* __restrict__ pg, const float* __restrict__ pbv,
    ushort_t* __restrict__ zo) {
  int lane = threadIdx.x & 63;
  int wid = threadIdx.x >> 6;
  int m = lane & 15;
  int q = lane >> 4;
  int node = blockIdx.x * 64 + wid * 16 + m;
  int valid = node < NN;
  int node_c = valid ? node : (NN - 1);
  size_t base = (size_t)node_c * DD;

  // z fragments (B-operand of GEMM1'), 4 k-groups
  const f16x8* Zf = (const f16x8*)(z + base);
  f16x8 zf[4];
#pragma unroll
  for (int kk = 0; kk < 4; kk++) zf[kk] = Zf[kk * 4 + q];

  // ---- GEMM1': A = W1^T frags, B = z frags. Batched loads per kk-group.
  const f16x8* W1f = (const f16x8*)W1p;
  f32x4 a1[8];
#pragma unroll
  for (int t = 0; t < 8; t++) a1[t] = (f32x4){0.f, 0.f, 0.f, 0.f};
#pragma unroll
  for (int kk = 0; kk < 4; kk++) {
    f16x8 wf[8];
#pragma unroll
    for (int t = 0; t < 8; t++) wf[t] = W1f[(t * 4 + kk) * 64 + lane];
#pragma unroll
    for (int t = 0; t < 8; t++)
      a1[t] = __builtin_amdgcn_mfma_f32_16x16x32_f16(wf[t], zf[kk], a1[t], 0, 0, 0);
  }

  // ---- bias + relu -> fp16, assembled directly into GEMM2 B-frags
  f16x8 tf[4];
#pragma unroll
  for (int t = 0; t < 8; t++) {
    float4 bb = *(const float4*)(b1 + t * 16 + q * 4);
    float bbr[4] = {bb.x, bb.y, bb.z, bb.w};
#pragma unroll
    for (int r = 0; r < 4; r++) {
      float v = fmaxf(a1[t][r] + bbr[r], 0.f);
      tf[t >> 1][(t & 1) * 4 + r] = (_Float16)v;
    }
  }

  // residual loads (fp16) issued here so latency hides under GEMM2's MFMAs
  ushort4 hr4[8];
#pragma unroll
  for (int t = 0; t < 8; t++) hr4[t] = *(const ushort4*)(hbin + base + t * 16 + q * 4);

  // ---- GEMM2': A = k-permuted W2^T frags, B = tf. Batched loads.
  const f16x8* W2f = (const f16x8*)W2p;
  f32x4 a2[8];
#pragma unroll
  for (int t = 0; t < 8; t++) a2[t] = (f32x4){0.f, 0.f, 0.f, 0.f};
#pragma unroll
  for (int g = 0; g < 4; g++) {
    f16x8 wf[8];
#pragma unroll
    for (int t = 0; t < 8; t++) wf[t] = W2f[(t * 4 + g) * 64 + lane];
#pragma unroll
    for (int t = 0; t < 8; t++)
      a2[t] = __builtin_amdgcn_mfma_f32_16x16x32_f16(wf[t], tf[g], a2[t], 0, 0, 0);
  }

  // ---- epilogue (per-node; lane holds dims 16t+4q+r of node)
  float s = 0.f, qs = 0.f;
#pragma unroll
  for (int t = 0; t < 8; t++) {
    float4 bb = *(const float4*)(b2 + t * 16 + q * 4);
    float bbr[4] = {bb.x, bb.y, bb.z, bb.w};
#pragma unroll
    for (int r = 0; r < 4; r++) {
      float u = a2[t][r] + bbr[r];
      a2[t][r] = u;
      s += u;
      qs += u * u;
    }
  }
  s += __shfl_xor(s, 16, 64);
  s += __shfl_xor(s, 32, 64);
  qs += __shfl_xor(qs, 16, 64);
  qs += __shfl_xor(qs, 32, 64);
  float mean = s * (1.0f / DD);
  float var = qs * (1.0f / DD) - mean * mean;
  float rstd = rsqrtf(var + LN_EPS);

  if (!LAST) {
#pragma unroll
    for (int t = 0; t < 8; t++) {
      float4 gg4 = *(const float4*)(lng + t * 16 + q * 4);
      float4 nb4 = *(const float4*)(lnb + t * 16 + q * 4);
      float ggr[4] = {gg4.x, gg4.y, gg4.z, gg4.w};
      float nbr[4] = {nb4.x, nb4.y, nb4.z, nb4.w};
      float hr[4] = {h2f(hr4[t].x), h2f(hr4[t].y), h2f(hr4[t].z), h2f(hr4[t].w)};
      float o[4];
#pragma unroll
      for (int r = 0; r < 4; r++) {
        float zz = (a2[t][r] - mean) * rstd * ggr[r] + nbr[r];
        o[r] = gelu_fast(zz) + hr[r];
      }
      if (valid) {
        ushort4 us;
        us.x = f2h(o[0]);
        us.y = f2h(o[1]);
        us.z = f2h(o[2]);
        us.w = f2h(o[3]);
        *(ushort4*)(hbout + base + t * 16 + q * 4) = us;
      }
    }
  } else {
    // hsum = (h1 + h2) + h3 in registers -> final pre-LN -> fp16 zo
    float w[8][4];
    float s2 = 0.f, q2 = 0.f;
#pragma unroll
    for (int t = 0; t < 8; t++) {
      float4 gg4 = *(const float4*)(lng + t * 16 + q * 4);
      float4 nb4 = *(const float4*)(lnb + t * 16 + q * 4);
      ushort4 hp4 = *(const ushort4*)(hbprev1 + base + t * 16 + q * 4);
      float ggr[4] = {gg4.x, gg4.y, gg4.z, gg4.w};
      float nbr[4] = {nb4.x, nb4.y, nb4.z, nb4.w};
      float hr[4] = {h2f(hr4[t].x), h2f(hr4[t].y), h2f(hr4[t].z), h2f(hr4[t].w)};
      float pr[4] = {h2f(hp4.x), h2f(hp4.y), h2f(hp4.z), h2f(hp4.w)};
#pragma unroll
      for (int r = 0; r < 4; r++) {
        float zz = (a2[t][r] - mean) * rstd * ggr[r] + nbr[r];
        float o = gelu_fast(zz) + hr[r];  // h3
        float wv = (pr[r] + hr[r]) + o;
        w[t][r] = wv;
        s2 += wv;
        q2 += wv * wv;
      }
    }
    s2 += __shfl_xor(s2, 16, 64);
    s2 += __shfl_xor(s2, 32, 64);
    q2 += __shfl_xor(q2, 16, 64);
    q2 += __shfl_xor(q2, 32, 64);
    float mean2 = s2 * (1.0f / DD);
    float var2 = q2 * (1.0f / DD) - mean2 * mean2;
    float rstd2 = rsqrtf(var2 + LN_EPS);
#pragma unroll
    for (int t = 0; t < 8; t++) {
      float4 pg4 = *(const float4*)(pg + t * 16 + q * 4);
      float4 pb4 = *(const float4*)(pbv + t * 16 + q * 4);
      float pgr[4] = {pg4.x, pg4.y, pg4.z, pg4.w};
      float pbr[4] = {pb4.x, pb4.y, pb4.z, pb4.w};
      float v0 = (w[t][0] - mean2) * rstd2 * pgr[0] + pbr[0];
      float v1 = (w[t][1] - mean2) * rstd2 * pgr[1] + pbr[1];
      float v2 = (w[t][2] - mean2) * rstd2 * pgr[2] + pbr[2];
      float v3 = (w[t][3] - mean2) * rstd2 * pgr[3] + pbr[3];
      if (valid) {
        ushort4 us;
        us.x = f2h(v0);
        us.y = f2h(v1);
        us.z = f2h(v2);
        us.w = f2h(v3);
        *(ushort4*)(zo + base + t * 16 + q * 4) = us;
      }
    }
  }
}

// ---------------- final GEMM: out = A*pW + pb, fp16 single-MFMA --------------
__global__ __launch_bounds__(256, 4) void k_mm(const ushort_t* __restrict__ zo,
                                               const ushort_t* __restrict__ Bp,
                                               const float* __restrict__ bias,
                                               float* __restrict__ out) {
  int lane = threadIdx.x & 63;
  int wid = threadIdx.x >> 6;
  int m = lane & 15;
  int q = lane >> 4;
  int node = blockIdx.x * 64 + wid * 16 + m;
  int valid = node < NN;
  int node_c = valid ? node : (NN - 1);
  size_t base = (size_t)node_c * DD;
  const f16x8* Zf = (const f16x8*)(zo + base);
  f16x8 zf[4];
#pragma unroll
  for (int kk = 0; kk < 4; kk++) zf[kk] = Zf[kk * 4 + q];
  const f16x8* Bf = (const f16x8*)Bp;
  f32x4 acc[8];
#pragma unroll
  for (int t = 0; t < 8; t++) acc[t] = (f32x4){0.f, 0.f, 0.f, 0.f};
#pragma unroll
  for (int kk = 0; kk < 4; kk++) {
    f16x8 wf[8];
#pragma unroll
    for (int t = 0; t < 8; t++) wf[t] = Bf[(t * 4 + kk) * 64 + lane];
#pragma unroll
    for (int t = 0; t < 8; t++)
      acc[t] = __builtin_amdgcn_mfma_f32_16x16x32_f16(wf[t], zf[kk], acc[t], 0, 0, 0);
  }
  if (valid) {
#pragma unroll
    for (int t = 0; t < 8; t++) {
      float4 bb = *(const float4*)(bias + t * 16 + q * 4);
      float4 o4;
      o4.x = acc[t][0] + bb.x;
      o4.y = acc[t][1] + bb.y;
      o4.z = acc[t][2] + bb.z;
      o4.w = acc[t][3] + bb.w;
      *(float4*)(out + base + t * 16 + q * 4) = o4;
    }
  }
}

extern "C" void kernel_launch(void* const* d_in, const int* in_sizes, int n_in, void* d_out,
                              int out_size, void* d_ws, size_t ws_size, hipStream_t stream) {
  (void)in_sizes;
  (void)n_in;
  (void)out_size;
  (void)ws_size;
  const float* x = (const float*)d_in[0];
  const int* ei = (const int*)d_in[1];
  const float* W1 = (const float*)d_in[2];
  const float* b1 = (const float*)d_in[3];
  const float* W2 = (const float*)d_in[4];
  const float* b2 = (const float*)d_in[5];
  const float* eps = (const float*)d_in[6];
  const float* lng = (const float*)d_in[7];
  const float* lnb = (const float*)d_in[8];
  const float* plg = (const float*)d_in[9];
  const float* plb = (const float*)d_in[10];
  const float* pW = (const float*)d_in[11];
  const float* pb = (const float*)d_in[12];
  float* out = (float*)d_out;

  char* ws = (char*)d_ws;
  ushort_t* hb0 = (ushort_t*)ws;
  ws += (size_t)NN * DD * 2;
  ushort_t* hb1 = (ushort_t*)ws;
  ws += (size_t)NN * DD * 2;
  ushort_t* hb2 = (ushort_t*)ws;
  ws += (size_t)NN * DD * 2;
  ushort_t* z = (ushort_t*)ws;
  ws += (size_t)NN * DD * 2;
  ushort_t* zo = (ushort_t*)ws;
  ws += (size_t)NN * DD * 2;
  ushort_t* wp = (ushort_t*)ws;
  ws += (size_t)7 * 16384 * 2;
  int* deg = (int*)ws;
  ws += (size_t)NN * 4;
  int* rowst = (int*)ws;
  ws += (size_t)(NN + 1) * 4 + 60;
  int* bsum = (int*)ws;
  ws += 512;
  int* csr = (int*)ws;
  ws += (size_t)NE * 4;
  int* epos = (int*)ws;
  ws += (size_t)NE * 4;

  const int* srcv = ei;
  const int* dstv = ei + NE;

  hipMemsetAsync(deg, 0, (size_t)NN * 4, stream);
  k_count<<<(NE + 255) / 256, 256, 0, stream>>>(dstv, deg, epos);
  k_block_sums<<<98, 256, 0, stream>>>(deg, bsum);
  k_scan_sums<<<1, 128, 0, stream>>>(bsum, 98);
  k_scan_write<<<98, 256, 0, stream>>>(deg, bsum, rowst);
  k_fill<<<4096, 256, 0, stream>>>(srcv, dstv, rowst, epos, csr);
  k_pack<<<448, 256, 0, stream>>>(W1, W2, pW, wp);
  k_cast<<<(NN * DD / 4 + 255) / 256, 256, 0, stream>>>(x, hb0);

  int mlp_grid = (NN + 63) / 64;  // 1563, 4 waves/block, 16 nodes/wave
  ushort_t* hbs[NL + 1] = {hb0, hb1, hb2, nullptr};
  for (int l = 0; l < NL; l++) {
    k_gather<<<NN / 4, 256, 0, stream>>>(hbs[l], rowst, csr, eps, l, (unsigned*)z);
    if (l < NL - 1) {
      k_mlp<0><<<mlp_grid, 256, 0, stream>>>(
          z, wp + (size_t)(2 * l) * 16384, wp + (size_t)(2 * l + 1) * 16384, b1 + l * DD,
          b2 + l * DD, lng + l * DD, lnb + l * DD, hbs[l], hb1, hbs[l + 1], plg, plb, zo);
    } else {
      k_mlp<1><<<mlp_grid, 256, 0, stream>>>(
          z, wp + (size_t)(2 * l) * 16384, wp + (size_t)(2 * l + 1) * 16384, b1 + l * DD,
          b2 + l * DD, lng + l * DD, lnb + l * DD, hbs[l], hb1, hb0, plg, plb, zo);
    }
  }
  k_mm<<<mlp_grid, 256, 0, stream>>>(zo, wp + (size_t)6 * 16384, pb, out);
}

// Round 11
// 574.661 us; speedup vs baseline: 1.3033x; 1.0155x over previous
//
#include <hip/hip_runtime.h>
#include <math.h>

#define NN 100000
#define NE 1600000
#define DD 128
#define NL 3
#define LN_EPS 1e-5f
#define NRANGE 8
#define RSZ (NN / NRANGE)  // 12500

typedef __attribute__((ext_vector_type(8))) _Float16 f16x8;
typedef __attribute__((ext_vector_type(4))) float f32x4;
typedef unsigned short ushort_t;

__device__ __forceinline__ unsigned short f2h(float f) {
  _Float16 h = (_Float16)f;
  unsigned short u;
  __builtin_memcpy(&u, &h, 2);
  return u;
}
__device__ __forceinline__ float h2f(unsigned short u) {
  _Float16 h;
  __builtin_memcpy(&h, &u, 2);
  return (float)h;
}
// gelu with fast erf (A&S 7.1.26, |err|<1.5e-7 -- far below tolerance)
__device__ __forceinline__ float gelu_fast(float x) {
  float xs = x * 0.7071067811865476f;
  float ax = fabsf(xs);
  float t = __builtin_amdgcn_rcpf(fmaf(0.3275911f, ax, 1.0f));
  float p = fmaf(t, 1.061405429f, -1.453152027f);
  p = fmaf(t, p, 1.421413741f);
  p = fmaf(t, p, -0.284496736f);
  p = fmaf(t, p, 0.254829592f);
  p = p * t;
  float e = __expf(-ax * ax);
  float er = fmaf(-p, e, 1.0f);
  er = copysignf(er, xs);
  return 0.5f * x * (1.0f + er);
}

// ---------------- CSR build ----------------
// ONE atomic pass: k_count records each edge's slot (epos). k_fill then has
// ZERO atomics and stays XCD-ranged so scatter stores merge in the local L2.
__global__ __launch_bounds__(256) void k_count(const int* __restrict__ dst,
                                               int* __restrict__ deg,
                                               int* __restrict__ epos) {
  int e = blockIdx.x * blockDim.x + threadIdx.x;
  if (e < NE) epos[e] = atomicAdd(&deg[dst[e]], 1);
}

__global__ void k_block_sums(const int* __restrict__ deg, int* __restrict__ bsum) {
  __shared__ int sh[256];
  int t = threadIdx.x;
  int base = blockIdx.x * 1024;
  int s = 0;
#pragma unroll
  for (int j = 0; j < 4; j++) {
    int idx = base + t * 4 + j;
    if (idx < NN) s += deg[idx];
  }
  sh[t] = s;
  __syncthreads();
  for (int off = 128; off > 0; off >>= 1) {
    if (t < off) sh[t] += sh[t + off];
    __syncthreads();
  }
  if (t == 0) bsum[blockIdx.x] = sh[0];
}

__global__ void k_scan_sums(int* __restrict__ bsum, int nb) {
  __shared__ int sh[128];
  int t = threadIdx.x;
  int v = (t < nb) ? bsum[t] : 0;
  int acc = v;
  sh[t] = v;
  __syncthreads();
  for (int off = 1; off < 128; off <<= 1) {
    int o = (t >= off) ? sh[t - off] : 0;
    __syncthreads();
    acc += o;
    sh[t] = acc;
    __syncthreads();
  }
  if (t < nb) bsum[t] = acc - v;  // exclusive
}

__global__ void k_scan_write(const int* __restrict__ deg, const int* __restrict__ bsum,
                             int* __restrict__ rowstart) {
  __shared__ int sh[256];
  int t = threadIdx.x;
  int base = blockIdx.x * 1024;
  int idx0 = base + t * 4;
  int v[4];
  int s = 0;
#pragma unroll
  for (int j = 0; j < 4; j++) {
    int idx = idx0 + j;
    v[j] = (idx < NN) ? deg[idx] : 0;
    s += v[j];
  }
  int acc = s;
  sh[t] = s;
  __syncthreads();
  for (int off = 1; off < 256; off <<= 1) {
    int o = (t >= off) ? sh[t - off] : 0;
    __syncthreads();
    acc += o;
    sh[t] = acc;
    __syncthreads();
  }
  int excl = acc - s + bsum[blockIdx.x];
#pragma unroll
  for (int j = 0; j < 4; j++) {
    int idx = idx0 + j;
    if (idx < NN) rowstart[idx] = excl;
    excl += v[j];
  }
  if (blockIdx.x == 0 && t == 0) rowstart[NN] = NE;
}

__global__ __launch_bounds__(256) void k_fill(const int* __restrict__ src,
                                              const int* __restrict__ dst,
                                              const int* __restrict__ rowstart,
                                              const int* __restrict__ epos,
                                              int* __restrict__ csr) {
  int range = blockIdx.x & (NRANGE - 1);
  int lo = range * RSZ;
  int hi = lo + RSZ;
  int nblk = gridDim.x >> 3;
  int bid = blockIdx.x >> 3;
  for (int e = bid * 256 + threadIdx.x; e < NE; e += nblk * 256) {
    int d = dst[e];
    if (d >= lo && d < hi) {
      csr[rowstart[d] + epos[e]] = src[e];
    }
  }
}

// ---------------- W pre-pack into MFMA A-of-W^T fragment order (fp16) --------
// W1, pW: k = 32kk + 8q + j (natural order).
// W2:     k = 32kk + 16(j>>2) + 4q + (j&3) -- permutation that makes the
//         GEMM2 B-fragment equal the GEMM1' accumulator layout (no LDS xpose).
__global__ void k_pack(const float* __restrict__ W1, const float* __restrict__ W2,
                       const float* __restrict__ pW, ushort_t* __restrict__ wp) {
  int id = blockIdx.x * 256 + threadIdx.x;  // 7*16384
  int mtx = id >> 14;                       // 0..6
  int r = id & 16383;
  const float* src;
  int perm = 0;
  if (mtx == 6) {
    src = pW;  // natural pack: k_mm consumes memory-layout B-frags
  } else {
    int layer = mtx >> 1;
    if (mtx & 1) {
      src = W2 + layer * 16384;
      perm = 1;
    } else {
      src = W1 + layer * 16384;
    }
  }
  int j = r & 7;
  int l = (r >> 3) & 63;
  int kk = (r >> 9) & 3;
  int t = r >> 11;
  int qq = (l >> 4) & 3;
  int k = perm ? (kk * 32 + ((j >> 2) << 4) + (qq << 2) + (j & 3))
               : (kk * 32 + (qq << 3) + j);
  int n = t * 16 + (l & 15);
  wp[id] = f2h(src[k * DD + n]);
}

// ---------------- x -> fp16 h0 ----------------
__global__ void k_cast(const float* __restrict__ x, ushort_t* __restrict__ hb) {
  int i = blockIdx.x * 256 + threadIdx.x;  // over NN*DD/4
  if (i < NN * DD / 4) {
    float4 v = ((const float4*)x)[i];
    ushort4 o;
    o.x = f2h(v.x);
    o.y = f2h(v.y);
    o.z = f2h(v.z);
    o.w = f2h(v.w);
    ((ushort4*)hb)[i] = o;
  }
}

// ---- gather: z = (1+eps)*hb[n] + sum_{incoming} hb[src] (fp16) -> fp16 z ----
// Half-wave per edge-stream: lane 8B (uint2), 32 lanes/row, the two halves of
// a wave process interleaved edge streams (k = s+g, s+g+2, ...). Per unrolled
// iteration the wave has 8 independent row-loads in flight (2x round-10's 4)
// and issues half the VMEM instructions per edge. Final shfl_xor(32) merge.
__global__ __launch_bounds__(256) void k_gather(const ushort_t* __restrict__ hb,
                                                const int* __restrict__ rowstart,
                                                const int* __restrict__ csr,
                                                const float* __restrict__ eps, int layer,
                                                uint2* __restrict__ z) {
  int n = blockIdx.x * 4 + (threadIdx.x >> 6);
  int lane = threadIdx.x & 63;
  int g = lane >> 5;  // half-wave: edge-stream parity
  int i = lane & 31;  // uint2 index within the 256B row
  const uint2* hb2 = (const uint2*)hb;

  float a0 = 0.f, a1 = 0.f, a2 = 0.f, a3 = 0.f;  // quad A (+ self on g==0)
  if (g == 0) {
    uint2 v = hb2[(size_t)n * 32 + i];
    float e1 = 1.0f + eps[layer];
    a0 = e1 * h2f((ushort_t)(v.x & 0xffffu));
    a1 = e1 * h2f((ushort_t)(v.x >> 16));
    a2 = e1 * h2f((ushort_t)(v.y & 0xffffu));
    a3 = e1 * h2f((ushort_t)(v.y >> 16));
  }
  float b0 = 0.f, b1 = 0.f, b2 = 0.f, b3 = 0.f;
  float c0 = 0.f, c1 = 0.f, c2 = 0.f, c3 = 0.f;
  float d0 = 0.f, d1 = 0.f, d2 = 0.f, d3 = 0.f;

  int s = rowstart[n], e = rowstart[n + 1];
  int k = s + g;
  for (; k + 6 < e; k += 8) {  // this half: edges k, k+2, k+4, k+6
    int i0 = csr[k], i1 = csr[k + 2], i2 = csr[k + 4], i3 = csr[k + 6];
    uint2 v0 = hb2[(size_t)i0 * 32 + i];
    uint2 v1 = hb2[(size_t)i1 * 32 + i];
    uint2 v2 = hb2[(size_t)i2 * 32 + i];
    uint2 v3 = hb2[(size_t)i3 * 32 + i];
    a0 += h2f((ushort_t)(v0.x & 0xffffu));
    a1 += h2f((ushort_t)(v0.x >> 16));
    a2 += h2f((ushort_t)(v0.y & 0xffffu));
    a3 += h2f((ushort_t)(v0.y >> 16));
    b0 += h2f((ushort_t)(v1.x & 0xffffu));
    b1 += h2f((ushort_t)(v1.x >> 16));
    b2 += h2f((ushort_t)(v1.y & 0xffffu));
    b3 += h2f((ushort_t)(v1.y >> 16));
    c0 += h2f((ushort_t)(v2.x & 0xffffu));
    c1 += h2f((ushort_t)(v2.x >> 16));
    c2 += h2f((ushort_t)(v2.y & 0xffffu));
    c3 += h2f((ushort_t)(v2.y >> 16));
    d0 += h2f((ushort_t)(v3.x & 0xffffu));
    d1 += h2f((ushort_t)(v3.x >> 16));
    d2 += h2f((ushort_t)(v3.y & 0xffffu));
    d3 += h2f((ushort_t)(v3.y >> 16));
  }
  for (; k < e; k += 2) {
    uint2 v = hb2[(size_t)csr[k] * 32 + i];
    a0 += h2f((ushort_t)(v.x & 0xffffu));
    a1 += h2f((ushort_t)(v.x >> 16));
    a2 += h2f((ushort_t)(v.y & 0xffffu));
    a3 += h2f((ushort_t)(v.y >> 16));
  }
  a0 += (b0 + c0) + d0;
  a1 += (b1 + c1) + d1;
  a2 += (b2 + c2) + d2;
  a3 += (b3 + c3) + d3;
  // merge the two edge-stream halves
  a0 += __shfl_xor(a0, 32, 64);
  a1 += __shfl_xor(a1, 32, 64);
  a2 += __shfl_xor(a2, 32, 64);
  a3 += __shfl_xor(a3, 32, 64);
  if (g == 0) {
    uint2 o;
    o.x = (unsigned)f2h(a0) | ((unsigned)f2h(a1) << 16);
    o.y = (unsigned)f2h(a2) | ((unsigned)f2h(a3) << 16);
    z[(size_t)n * 32 + i] = o;
  }
}

// ------- fused MLP: swapped-operand, LDS-free, fp16 single-MFMA --------------
template <int LAST>
__global__ __launch_bounds__(256, 4) void k_mlp(
    const ushort_t* __restrict__ z, const ushort_t* __restrict__ W1p,
    const ushort_t* __restrict__ W2p, const float* __restrict__ b1,
    const float* __restrict__ b2, const float* __restrict__ lng,
    const float* __restrict__ lnb, const ushort_t* __restrict__ hbin,
    const ushort_t* __restrict__ hbprev1, ushort_t* __restrict__ hbout,
    const float* __restrict__ pg, const float* __restrict__ pbv,
    ushort_t* __restrict__ zo) {
  int lane = threadIdx.x & 63;
  int wid = threadIdx.x >> 6;
  int m = lane & 15;
  int q = lane >> 4;
  int node = blockIdx.x * 64 + wid * 16 + m;
  int valid = node < NN;
  int node_c = valid ? node : (NN - 1);
  size_t base = (size_t)node_c * DD;

  // z fragments (B-operand of GEMM1'), 4 k-groups
  const f16x8* Zf = (const f16x8*)(z + base);
  f16x8 zf[4];
#pragma unroll
  for (int kk = 0; kk < 4; kk++) zf[kk] = Zf[kk * 4 + q];

  // ---- GEMM1': A = W1^T frags, B = z frags. Batched loads per kk-group.
  const f16x8* W1f = (const f16x8*)W1p;
  f32x4 a1[8];
#pragma unroll
  for (int t = 0; t < 8; t++) a1[t] = (f32x4){0.f, 0.f, 0.f, 0.f};
#pragma unroll
  for (int kk = 0; kk < 4; kk++) {
    f16x8 wf[8];
#pragma unroll
    for (int t = 0; t < 8; t++) wf[t] = W1f[(t * 4 + kk) * 64 + lane];
#pragma unroll
    for (int t = 0; t < 8; t++)
      a1[t] = __builtin_amdgcn_mfma_f32_16x16x32_f16(wf[t], zf[kk], a1[t], 0, 0, 0);
  }

  // ---- bias + relu -> fp16, assembled directly into GEMM2 B-frags
  f16x8 tf[4];
#pragma unroll
  for (int t = 0; t < 8; t++) {
    float4 bb = *(const float4*)(b1 + t * 16 + q * 4);
    float bbr[4] = {bb.x, bb.y, bb.z, bb.w};
#pragma unroll
    for (int r = 0; r < 4; r++) {
      float v = fmaxf(a1[t][r] + bbr[r], 0.f);
      tf[t >> 1][(t & 1) * 4 + r] = (_Float16)v;
    }
  }

  // residual loads (fp16) issued here so latency hides under GEMM2's MFMAs
  ushort4 hr4[8];
#pragma unroll
  for (int t = 0; t < 8; t++) hr4[t] = *(const ushort4*)(hbin + base + t * 16 + q * 4);

  // ---- GEMM2': A = k-permuted W2^T frags, B = tf. Batched loads.
  const f16x8* W2f = (const f16x8*)W2p;
  f32x4 a2[8];
#pragma unroll
  for (int t = 0; t < 8; t++) a2[t] = (f32x4){0.f, 0.f, 0.f, 0.f};
#pragma unroll
  for (int g = 0; g < 4; g++) {
    f16x8 wf[8];
#pragma unroll
    for (int t = 0; t < 8; t++) wf[t] = W2f[(t * 4 + g) * 64 + lane];
#pragma unroll
    for (int t = 0; t < 8; t++)
      a2[t] = __builtin_amdgcn_mfma_f32_16x16x32_f16(wf[t], tf[g], a2[t], 0, 0, 0);
  }

  // ---- epilogue (per-node; lane holds dims 16t+4q+r of node)
  float s = 0.f, qs = 0.f;
#pragma unroll
  for (int t = 0; t < 8; t++) {
    float4 bb = *(const float4*)(b2 + t * 16 + q * 4);
    float bbr[4] = {bb.x, bb.y, bb.z, bb.w};
#pragma unroll
    for (int r = 0; r < 4; r++) {
      float u = a2[t][r] + bbr[r];
      a2[t][r] = u;
      s += u;
      qs += u * u;
    }
  }
  s += __shfl_xor(s, 16, 64);
  s += __shfl_xor(s, 32, 64);
  qs += __shfl_xor(qs, 16, 64);
  qs += __shfl_xor(qs, 32, 64);
  float mean = s * (1.0f / DD);
  float var = qs * (1.0f / DD) - mean * mean;
  float rstd = rsqrtf(var + LN_EPS);

  if (!LAST) {
#pragma unroll
    for (int t = 0; t < 8; t++) {
      float4 gg4 = *(const float4*)(lng + t * 16 + q * 4);
      float4 nb4 = *(const float4*)(lnb + t * 16 + q * 4);
      float ggr[4] = {gg4.x, gg4.y, gg4.z, gg4.w};
      float nbr[4] = {nb4.x, nb4.y, nb4.z, nb4.w};
      float hr[4] = {h2f(hr4[t].x), h2f(hr4[t].y), h2f(hr4[t].z), h2f(hr4[t].w)};
      float o[4];
#pragma unroll
      for (int r = 0; r < 4; r++) {
        float zz = (a2[t][r] - mean) * rstd * ggr[r] + nbr[r];
        o[r] = gelu_fast(zz) + hr[r];
      }
      if (valid) {
        ushort4 us;
        us.x = f2h(o[0]);
        us.y = f2h(o[1]);
        us.z = f2h(o[2]);
        us.w = f2h(o[3]);
        *(ushort4*)(hbout + base + t * 16 + q * 4) = us;
      }
    }
  } else {
    // hsum = (h1 + h2) + h3 in registers -> final pre-LN -> fp16 zo
    float w[8][4];
    float s2 = 0.f, q2 = 0.f;
#pragma unroll
    for (int t = 0; t < 8; t++) {
      float4 gg4 = *(const float4*)(lng + t * 16 + q * 4);
      float4 nb4 = *(const float4*)(lnb + t * 16 + q * 4);
      ushort4 hp4 = *(const ushort4*)(hbprev1 + base + t * 16 + q * 4);
      float ggr[4] = {gg4.x, gg4.y, gg4.z, gg4.w};
      float nbr[4] = {nb4.x, nb4.y, nb4.z, nb4.w};
      float hr[4] = {h2f(hr4[t].x), h2f(hr4[t].y), h2f(hr4[t].z), h2f(hr4[t].w)};
      float pr[4] = {h2f(hp4.x), h2f(hp4.y), h2f(hp4.z), h2f(hp4.w)};
#pragma unroll
      for (int r = 0; r < 4; r++) {
        float zz = (a2[t][r] - mean) * rstd * ggr[r] + nbr[r];
        float o = gelu_fast(zz) + hr[r];  // h3
        float wv = (pr[r] + hr[r]) + o;
        w[t][r] = wv;
        s2 += wv;
        q2 += wv * wv;
      }
    }
    s2 += __shfl_xor(s2, 16, 64);
    s2 += __shfl_xor(s2, 32, 64);
    q2 += __shfl_xor(q2, 16, 64);
    q2 += __shfl_xor(q2, 32, 64);
    float mean2 = s2 * (1.0f / DD);
    float var2 = q2 * (1.0f / DD) - mean2 * mean2;
    float rstd2 = rsqrtf(var2 + LN_EPS);
#pragma unroll
    for (int t = 0; t < 8; t++) {
      float4 pg4 = *(const float4*)(pg + t * 16 + q * 4);
      float4 pb4 = *(const float4*)(pbv + t * 16 + q * 4);
      float pgr[4] = {pg4.x, pg4.y, pg4.z, pg4.w};
      float pbr[4] = {pb4.x, pb4.y, pb4.z, pb4.w};
      float v0 = (w[t][0] - mean2) * rstd2 * pgr[0] + pbr[0];
      float v1 = (w[t][1] - mean2) * rstd2 * pgr[1] + pbr[1];
      float v2 = (w[t][2] - mean2) * rstd2 * pgr[2] + pbr[2];
      float v3 = (w[t][3] - mean2) * rstd2 * pgr[3] + pbr[3];
      if (valid) {
        ushort4 us;
        us.x = f2h(v0);
        us.y = f2h(v1);
        us.z = f2h(v2);
        us.w = f2h(v3);
        *(ushort4*)(zo + base + t * 16 + q * 4) = us;
      }
    }
  }
}

// ---------------- final GEMM: out = A*pW + pb, fp16 single-MFMA --------------
__global__ __launch_bounds__(256, 4) void k_mm(const ushort_t* __restrict__ zo,
                                               const ushort_t* __restrict__ Bp,
                                               const float* __restrict__ bias,
                                               float* __restrict__ out) {
  int lane = threadIdx.x & 63;
  int wid = threadIdx.x >> 6;
  int m = lane & 15;
  int q = lane >> 4;
  int node = blockIdx.x * 64 + wid * 16 + m;
  int valid = node < NN;
  int node_c = valid ? node : (NN - 1);
  size_t base = (size_t)node_c * DD;
  const f16x8* Zf = (const f16x8*)(zo + base);
  f16x8 zf[4];
#pragma unroll
  for (int kk = 0; kk < 4; kk++) zf[kk] = Zf[kk * 4 + q];
  const f16x8* Bf = (const f16x8*)Bp;
  f32x4 acc[8];
#pragma unroll
  for (int t = 0; t < 8; t++) acc[t] = (f32x4){0.f, 0.f, 0.f, 0.f};
#pragma unroll
  for (int kk = 0; kk < 4; kk++) {
    f16x8 wf[8];
#pragma unroll
    for (int t = 0; t < 8; t++) wf[t] = Bf[(t * 4 + kk) * 64 + lane];
#pragma unroll
    for (int t = 0; t < 8; t++)
      acc[t] = __builtin_amdgcn_mfma_f32_16x16x32_f16(wf[t], zf[kk], acc[t], 0, 0, 0);
  }
  if (valid) {
#pragma unroll
    for (int t = 0; t < 8; t++) {
      float4 bb = *(const float4*)(bias + t * 16 + q * 4);
      float4 o4;
      o4.x = acc[t][0] + bb.x;
      o4.y = acc[t][1] + bb.y;
      o4.z = acc[t][2] + bb.z;
      o4.w = acc[t][3] + bb.w;
      *(float4*)(out + base + t * 16 + q * 4) = o4;
    }
  }
}

extern "C" void kernel_launch(void* const* d_in, const int* in_sizes, int n_in, void* d_out,
                              int out_size, void* d_ws, size_t ws_size, hipStream_t stream) {
  (void)in_sizes;
  (void)n_in;
  (void)out_size;
  (void)ws_size;
  const float* x = (const float*)d_in[0];
  const int* ei = (const int*)d_in[1];
  const float* W1 = (const float*)d_in[2];
  const float* b1 = (const float*)d_in[3];
  const float* W2 = (const float*)d_in[4];
  const float* b2 = (const float*)d_in[5];
  const float* eps = (const float*)d_in[6];
  const float* lng = (const float*)d_in[7];
  const float* lnb = (const float*)d_in[8];
  const float* plg = (const float*)d_in[9];
  const float* plb = (const float*)d_in[10];
  const float* pW = (const float*)d_in[11];
  const float* pb = (const float*)d_in[12];
  float* out = (float*)d_out;

  char* ws = (char*)d_ws;
  ushort_t* hb0 = (ushort_t*)ws;
  ws += (size_t)NN * DD * 2;
  ushort_t* hb1 = (ushort_t*)ws;
  ws += (size_t)NN * DD * 2;
  ushort_t* hb2 = (ushort_t*)ws;
  ws += (size_t)NN * DD * 2;
  ushort_t* z = (ushort_t*)ws;
  ws += (size_t)NN * DD * 2;
  ushort_t* zo = (ushort_t*)ws;
  ws += (size_t)NN * DD * 2;
  ushort_t* wp = (ushort_t*)ws;
  ws += (size_t)7 * 16384 * 2;
  int* deg = (int*)ws;
  ws += (size_t)NN * 4;
  int* rowst = (int*)ws;
  ws += (size_t)(NN + 1) * 4 + 60;
  int* bsum = (int*)ws;
  ws += 512;
  int* csr = (int*)ws;
  ws += (size_t)NE * 4;
  int* epos = (int*)ws;
  ws += (size_t)NE * 4;

  const int* srcv = ei;
  const int* dstv = ei + NE;

  hipMemsetAsync(deg, 0, (size_t)NN * 4, stream);
  k_count<<<(NE + 255) / 256, 256, 0, stream>>>(dstv, deg, epos);
  k_block_sums<<<98, 256, 0, stream>>>(deg, bsum);
  k_scan_sums<<<1, 128, 0, stream>>>(bsum, 98);
  k_scan_write<<<98, 256, 0, stream>>>(deg, bsum, rowst);
  k_fill<<<4096, 256, 0, stream>>>(srcv, dstv, rowst, epos, csr);
  k_pack<<<448, 256, 0, stream>>>(W1, W2, pW, wp);
  k_cast<<<(NN * DD / 4 + 255) / 256, 256, 0, stream>>>(x, hb0);

  int mlp_grid = (NN + 63) / 64;  // 1563, 4 waves/block, 16 nodes/wave
  ushort_t* hbs[NL + 1] = {hb0, hb1, hb2, nullptr};
  for (int l = 0; l < NL; l++) {
    k_gather<<<NN / 4, 256, 0, stream>>>(hbs[l], rowst, csr, eps, l, (uint2*)z);
    if (l < NL - 1) {
      k_mlp<0><<<mlp_grid, 256, 0, stream>>>(
          z, wp + (size_t)(2 * l) * 16384, wp + (size_t)(2 * l + 1) * 16384, b1 + l * DD,
          b2 + l * DD, lng + l * DD, lnb + l * DD, hbs[l], hb1, hbs[l + 1], plg, plb, zo);
    } else {
      k_mlp<1><<<mlp_grid, 256, 0, stream>>>(
          z, wp + (size_t)(2 * l) * 16384, wp + (size_t)(2 * l + 1) * 16384, b1 + l * DD,
          b2 + l * DD, lng + l * DD, lnb + l * DD, hbs[l], hb1, hb0, plg, plb, zo);
    }
  }
  k_mm<<<mlp_grid, 256, 0, stream>>>(zo, wp + (size_t)6 * 16384, pb, out);
}